// Round 19
// baseline (116.021 us; speedup 1.0000x reference)
//
#include <hip/hip_runtime.h>
#include <hip/hip_bf16.h>

#define BB 512
#define NN 714
#define EE 4096
#define ED2 62
#define CH 32
#define NT16 45    // ceil(NN/16)
#define NPAD 720   // NT16*16
#define VOCAB 38733
#define NPRE 1211  // ceil(VOCAB/32) blocks for emb@W1 precompute
#define ELLR 432   // ELL row capacity (rows of 16 u16), rows per tile padded to x4
#define ELLB (ELLR*16)

typedef unsigned int u32;
typedef unsigned short u16;
typedef short short8 __attribute__((ext_vector_type(8)));
typedef float float4v __attribute__((ext_vector_type(4)));
typedef _Float16 f16x2 __attribute__((ext_vector_type(2)));
typedef __fp16 fp16x2 __attribute__((ext_vector_type(2)));

__device__ __forceinline__ u32 f2bf(float f) {
  u32 u = __float_as_uint(f);
  return (u + 0x7fffu + ((u >> 16) & 1u)) >> 16;
}
__device__ __forceinline__ u32 pack2(float a, float b) {
  return f2bf(a) | (f2bf(b) << 16);
}
__device__ __forceinline__ f16x2 u2h(u32 x) { union { u32 u; f16x2 h; } c; c.u = x; return c.h; }
__device__ __forceinline__ u32 packh(float a, float b) {
  union { fp16x2 h; u32 u; } c;
  c.h = __builtin_amdgcn_cvt_pkrtz(a, b);
  return c.u;
}
__device__ __forceinline__ u16 f2h(float a) {
  union { __fp16 h; u16 u; } c;
  c.h = (__fp16)a;
  return c.u;
}

// y-in-LDS swizzle: uint4 slot q of node -> q ^ ((node>>1)&3).
__device__ __forceinline__ int yslot(int node, int q) {
  return (node << 2) | (q ^ ((node >> 1) & 3));
}

// ---------------- Fused setup kernel ----------------
// blocks [0, NPRE): T0/T1 = emb @ W1[0:62]/W1[62:124] -> fp16 [2][VOCAB][32]
// blocks [NPRE, NPRE+BB): per-batch degree/dinv/perm/ELL prep
__global__ __launch_bounds__(256) void k_setup(const float* __restrict__ emb,
    const float* __restrict__ W1, u16* __restrict__ Tg,
    const int* __restrict__ edges,
    float* __restrict__ dinv, u16* __restrict__ perm_g,
    u16* __restrict__ ell_g, u16* __restrict__ elloff_g)
{
  const int tid = threadIdx.x;
  if (blockIdx.x < NPRE) {
    __shared__ float sW[124 * 32];
    for (int i = tid; i < 124 * 32; i += 256) sW[i] = W1[i];
    __syncthreads();
    const int wv = tid >> 6, lane = tid & 63;
    const int tbl = lane >> 5, ch = lane & 31;
    const float* __restrict__ wbase = sW + tbl * 62 * 32 + ch;
#pragma unroll 1
    for (int it = 0; it < 8; ++it) {
      const int r = blockIdx.x * 32 + it * 4 + wv;
      if (r < VOCAB) {
        const float2* __restrict__ er = (const float2*)(emb + (size_t)r * ED2);
        float acc = 0.f;
#pragma unroll 31
        for (int k2 = 0; k2 < 31; ++k2) {
          float2 e = er[k2];
          acc = fmaf(e.x, wbase[(2 * k2) * 32], acc);
          acc = fmaf(e.y, wbase[(2 * k2 + 1) * 32], acc);
        }
        Tg[((size_t)tbl * VOCAB + r) * 32 + ch] = f2h(acc);
      }
    }
    return;
  }
  const int b = blockIdx.x - NPRE;
  const int* __restrict__ er = edges + (size_t)b * 2 * EE;       // e[0] = source (row)
  const int* __restrict__ ec = er + EE;                          // e[1] = target (col)
  __shared__ int s_cnt[NN];
  __shared__ int s_a[1024];
  __shared__ int s_b[1024];
  __shared__ u16 s_rows16[EE];
  __shared__ u16 s_perm[NPAD];
  __shared__ u16 s_degP[NPAD];
  __shared__ int s_hist[64];
  __shared__ int s_md[NT16 + 1];

  for (int i = tid; i < NN; i += 256) s_cnt[i] = 0;
  __syncthreads();
  for (int e = tid; e < EE; e += 256) atomicAdd(&s_cnt[ec[e]], 1);
  __syncthreads();
  for (int i = tid; i < 1024; i += 256) s_a[i] = (i < NN) ? s_cnt[i] : 0;
  for (int i = tid; i < NN; i += 256)
    dinv[(size_t)b * NN + i] = rsqrtf((float)(s_cnt[i] + 1));    // +1 self loop
  __syncthreads();
  int* src = s_a; int* dst = s_b;
  for (int d = 1; d < 1024; d <<= 1) {
    for (int i = tid; i < 1024; i += 256) {
      int v = src[i];
      if (i >= d) v += src[i - d];
      dst[i] = v;
    }
    __syncthreads();
    int* t = src; src = dst; dst = t;
  }
  // src (= s_a, 10 swaps) = inclusive scan of degree counts
  for (int i = tid; i < NN; i += 256) s_cnt[i] = 0;  // fill cursors
  __syncthreads();
  for (int e = tid; e < EE; e += 256) {
    int c = ec[e];
    int p = atomicAdd(&s_cnt[c], 1);
    int base = (c == 0) ? 0 : src[c - 1];
    s_rows16[base + p] = (u16)er[e];
  }
  // degree-sorted perm (counting sort, 64 bins)
  for (int i = tid; i < 64; i += 256) s_hist[i] = 0;
  for (int i = tid; i < NPAD; i += 256) { s_perm[i] = 0xFFFFu; s_degP[i] = 0; }
  __syncthreads();
  for (int i = tid; i < NN; i += 256) {
    int deg = src[i] - (i ? src[i - 1] : 0);
    atomicAdd(&s_hist[deg < 63 ? deg : 63], 1);
  }
  __syncthreads();
  // wave-parallel exclusive scan of the 64 histogram bins
  if (tid < 64) {
    int v = s_hist[tid];
    int incl = v;
#pragma unroll
    for (int d = 1; d < 64; d <<= 1) {
      int o = __shfl_up(incl, d, 64);
      if (tid >= d) incl += o;
    }
    s_hist[tid] = incl - v;
  }
  __syncthreads();
  for (int i = tid; i < NN; i += 256) {
    int deg = src[i] - (i ? src[i - 1] : 0);
    int pos = atomicAdd(&s_hist[deg < 63 ? deg : 63], 1);
    s_perm[pos] = (u16)i;
    s_degP[pos] = (u16)deg;
  }
  __syncthreads();
  for (int i = tid; i < NPAD; i += 256) perm_g[(size_t)b * NPAD + i] = s_perm[i];
  // per-tile max degree, padded to multiple of 4
  if (tid < NT16) {
    int md = 0;
#pragma unroll
    for (int c = 0; c < 16; ++c) { int d = s_degP[tid * 16 + c]; md = d > md ? d : md; }
    s_md[tid] = (md + 3) & ~3;
  }
  __syncthreads();
  // wave-parallel exclusive scan of the 45 tile sizes (clamped to ELLR)
  if (tid < 64) {
    int m = (tid < NT16) ? s_md[tid] : 0;
    int incl = m;
#pragma unroll
    for (int d = 1; d < 64; d <<= 1) {
      int o = __shfl_up(incl, d, 64);
      if (tid >= d) incl += o;
    }
    int excl = incl - m;
    if (excl > ELLR) excl = ELLR;
    if (tid < NT16) s_md[tid] = excl;
    if (tid == NT16 - 1) s_md[NT16] = (incl > ELLR) ? ELLR : incl;
  }
  __syncthreads();
  if (tid <= NT16) elloff_g[(size_t)b * (NT16 + 1) + tid] = (u16)s_md[tid];
  // fill ELL per-wave (wave w takes tiles w, w+4, ...), PRE-SWIZZLED entries (pad -> dummy NN)
  {
    const int wv4 = tid >> 6, lane = tid & 63;
    u16* eg = ell_g + (size_t)b * ELLB;
    for (int t = wv4; t < NT16; t += 4) {
      const int base = s_md[t], md4 = s_md[t + 1] - base;
      for (int s = lane; s < md4 * 16; s += 64) {
        const int kk = s >> 4, col = s & 15;
        const int pv = s_perm[t * 16 + col];
        int r = NN;
        if (pv != 0xFFFF) {
          const int deg = s_degP[t * 16 + col];
          if (kk < deg) {
            const int off = pv ? src[pv - 1] : 0;
            r = (int)s_rows16[off + kk];
          }
        }
        eg[base * 16 + s] = (u16)((r << 2) | ((r >> 1) & 3));
      }
    }
  }
}

// ---------------- Kernel B: GCN1 via precomputed tables: y1 = dinv*(T0[id0]+T1[id1]+cont@Wc) ----------------
__global__ __launch_bounds__(256) void k_gcn1v(
    const int* __restrict__ ids, const float* __restrict__ cont,
    const u16* __restrict__ T, const float* __restrict__ W1,
    const float* __restrict__ dinv, u32* __restrict__ y1)
{
  const int idx = blockIdx.x * 256 + threadIdx.x;   // BB*NN = 1428*256 exactly
  __shared__ float sWc[96];
  if (threadIdx.x < 96) sWc[threadIdx.x] = W1[124 * 32 + threadIdx.x];
  __syncthreads();
  const int2 id2 = ((const int2*)ids)[idx];
  const uint4* __restrict__ t0 = (const uint4*)(T + (size_t)id2.x * 32);
  const uint4* __restrict__ t1 = (const uint4*)(T + ((size_t)VOCAB + id2.y) * 32);
  uint4 q0 = t0[0], q1 = t0[1], q2 = t0[2], q3 = t0[3];
  uint4 r0 = t1[0], r1 = t1[1], r2 = t1[2], r3 = t1[3];
  const float* __restrict__ c3 = cont + (size_t)idx * 3;
  const float c0 = c3[0], c1 = c3[1], c2 = c3[2];
  const float dv = dinv[idx];
  const u32 qs[16] = { q0.x, q0.y, q0.z, q0.w, q1.x, q1.y, q1.z, q1.w,
                       q2.x, q2.y, q2.z, q2.w, q3.x, q3.y, q3.z, q3.w };
  const u32 rs[16] = { r0.x, r0.y, r0.z, r0.w, r1.x, r1.y, r1.z, r1.w,
                       r2.x, r2.y, r2.z, r2.w, r3.x, r3.y, r3.z, r3.w };
  u32 os[16];
#pragma unroll
  for (int s = 0; s < 16; ++s) {
    f16x2 a = u2h(qs[s]);
    f16x2 bb = u2h(rs[s]);
    const int ch = 2 * s;
    float v0 = (float)a.x + (float)bb.x;
    float v1 = (float)a.y + (float)bb.y;
    v0 = fmaf(c0, sWc[ch],      v0);
    v1 = fmaf(c0, sWc[ch + 1],  v1);
    v0 = fmaf(c1, sWc[32 + ch],     v0);
    v1 = fmaf(c1, sWc[32 + ch + 1], v1);
    v0 = fmaf(c2, sWc[64 + ch],     v0);
    v1 = fmaf(c2, sWc[64 + ch + 1], v1);
    os[s] = packh(v0 * dv, v1 * dv);
  }
  uint4* op = (uint4*)(y1 + (size_t)idx * 16);
#pragma unroll
  for (int s4 = 0; s4 < 4; ++s4) {
    uint4 w = { os[4 * s4], os[4 * s4 + 1], os[4 * s4 + 2], os[4 * s4 + 3] };
    op[s4] = w;
  }
}

// ---------------- Fused kernel: layers 2,3,4 + tail ----------------
// y in LDS is fp16; aggregation via v_pk_add_f16 with DUAL accumulator sets
// (even/odd edges -> a*/b*, merged at f32 flush every 16 edges).
// ELL entries pre-swizzled: a16 = e0 ^ kg.
#define EDGEA(EP, K) { const int a16 = ((int)(EP)[(K) * 16]) ^ kg; \
  uint4 n = sy4[a16]; \
  a0h += u2h(n.x); a1h += u2h(n.y); a2h += u2h(n.z); a3h += u2h(n.w); }
#define EDGEB(EP, K) { const int a16 = ((int)(EP)[(K) * 16]) ^ kg; \
  uint4 n = sy4[a16]; \
  b0h += u2h(n.x); b1h += u2h(n.y); b2h += u2h(n.z); b3h += u2h(n.w); }
#define FLUSH { a0h += b0h; a1h += b1h; a2h += b2h; a3h += b3h; \
  zx[0] += (float)a0h.x; zx[1] += (float)a0h.y; \
  zx[2] += (float)a1h.x; zx[3] += (float)a1h.y; \
  zx[4] += (float)a2h.x; zx[5] += (float)a2h.y; \
  zx[6] += (float)a3h.x; zx[7] += (float)a3h.y; \
  a0h = hz; a1h = hz; a2h = hz; a3h = hz; \
  b0h = hz; b1h = hz; b2h = hz; b3h = hz; }
#define AGG_LOOP(EP) { int kk = 0; \
  while (kk + 16 <= md4) { \
    _Pragma("unroll") for (int e = 0; e < 16; e += 2) { EDGEA(EP, kk + e) EDGEB(EP, kk + e + 1) } \
    FLUSH \
    kk += 16; } \
  if (kk + 8 <= md4) { \
    _Pragma("unroll") for (int e = 0; e < 8; e += 2) { EDGEA(EP, kk + e) EDGEB(EP, kk + e + 1) } \
    FLUSH \
    kk += 8; } \
  if (kk < md4) { \
    _Pragma("unroll") for (int e = 0; e < 4; e += 2) { EDGEA(EP, kk + e) EDGEB(EP, kk + e + 1) } \
    FLUSH } }

template<int ACT>
__device__ __forceinline__ void gcn_pass32(
    u32* __restrict__ sy, const u16* __restrict__ s_ell,
    const u16* __restrict__ s_elloff, const float* __restrict__ s_dv,
    const u16* __restrict__ pvs,
    const int wv, const int col, const int kg,
    const short8 a0v, const short8 a1v, const float* __restrict__ bias8)
{
  const uint4* sy4 = (const uint4*)sy;
  const f16x2 hz = {(_Float16)0, (_Float16)0};
  u32 outs[3][4];
  int nodes[3];
#pragma unroll
  for (int p = 0; p < 3; ++p) {
    const int t = p * 16 + wv;
    const int pv = (t < NT16) ? (int)pvs[p] : 0xFFFF;
    const int node = (pv == 0xFFFF) ? NN : pv;
    nodes[p] = (pv == 0xFFFF) ? -1 : pv;
    int base = 0, md4 = 0;
    if (t < NT16) { base = s_elloff[t]; md4 = s_elloff[t + 1] - base; }
    base = __builtin_amdgcn_readfirstlane(base);
    md4 = __builtin_amdgcn_readfirstlane(md4);
    f16x2 a0h, a1h, a2h, a3h;
    f16x2 b0h = hz, b1h = hz, b2h = hz, b3h = hz;
    {
      uint4 u = sy4[yslot(node, kg)];          // self (dummy row = zeros)
      a0h = u2h(u.x); a1h = u2h(u.y); a2h = u2h(u.z); a3h = u2h(u.w);
    }
    float zx[8];
#pragma unroll
    for (int j = 0; j < 8; ++j) zx[j] = 0.f;
    const u16* ep = s_ell + base * 16 + col;
    AGG_LOOP(ep)
    const float dv = s_dv[node];               // dummy dv = 0
    float h[8];
#pragma unroll
    for (int j = 0; j < 8; ++j) {
      float t2 = fmaf(dv, zx[j], bias8[j]);
      float l = (t2 > 0.f) ? t2 : 0.01f * t2;
      h[j] = (ACT == 0) ? l : (l + t2);
    }
    union { u32 u[4]; short8 v; } ub;
#pragma unroll
    for (int jj = 0; jj < 4; ++jj) ub.u[jj] = pack2(h[2 * jj], h[2 * jj + 1]);
    float4v z4 = {0.f, 0.f, 0.f, 0.f};
    float4v d0 = __builtin_amdgcn_mfma_f32_16x16x32_bf16(a0v, ub.v, z4, 0, 0, 0);
    float4v d1 = __builtin_amdgcn_mfma_f32_16x16x32_bf16(a1v, ub.v, z4, 0, 0, 0);
    outs[p][0] = packh(d0[0] * dv, d0[1] * dv);
    outs[p][1] = packh(d0[2] * dv, d0[3] * dv);
    outs[p][2] = packh(d1[0] * dv, d1[1] * dv);
    outs[p][3] = packh(d1[2] * dv, d1[3] * dv);
  }
  __syncthreads();
#pragma unroll
  for (int p = 0; p < 3; ++p) {
    const int node = nodes[p];
    if (node >= 0) {
      const int sw = (node >> 1) & 3;
      u32* op = sy + node * 16;
      uint2 s0 = { outs[p][0], outs[p][1] };
      uint2 s1 = { outs[p][2], outs[p][3] };
      *(uint2*)(op + (((kg >> 1) ^ sw) << 2) + ((2 * kg) & 3)) = s0;
      *(uint2*)(op + (((2 + (kg >> 1)) ^ sw) << 2) + ((2 * kg) & 3)) = s1;
    }
  }
  __syncthreads();
}

__global__ __launch_bounds__(1024) void k_fused(
    const u32* __restrict__ yin, const float* __restrict__ dinv,
    const u16* __restrict__ perm_g, const u16* __restrict__ ell_g,
    const u16* __restrict__ elloff_g,
    const float* __restrict__ b1, const float* __restrict__ W2,
    const float* __restrict__ b2, const float* __restrict__ W3,
    const float* __restrict__ b3, const float* __restrict__ W4,
    const float* __restrict__ b4, const float* __restrict__ Wf1,
    const float* __restrict__ bf1, const float* __restrict__ Wf2,
    const float* __restrict__ bf2, float* __restrict__ out)
{
  const int b = blockIdx.x;
  const int tid = threadIdx.x;
  const int lane = tid & 63;
  const int wv = tid >> 6;          // wave 0..15
  const int col = lane & 15;
  const int kg = lane >> 4;

  __shared__ __align__(16) char smem[65408];
  u32*   s_y      = (u32*)smem;                     // 45760 B (715 rows; dead later)
  u16*   s_ell    = (u16*)(smem + 45760);           // 13824
  u16*   s_elloff = (u16*)(smem + 59584);           // 96
  float* s_dv     = (float*)(smem + 59680);         // 2864 (incl dummy)
  float* s_h      = (float*)(smem + 62544);         // 2864 (incl dummy)
  float* s_red    = (float*)smem;                   // aliases dead s_y
  float* s_u      = (float*)(smem + 8192);          // aliases dead s_y

  {
    const uint4* __restrict__ ysrc = (const uint4*)(yin + (size_t)b * NN * 16);
    uint4* sy4w = (uint4*)s_y;
    const uint4 z4 = {0, 0, 0, 0};
    for (int s = tid; s < (NN + 1) * 4; s += 1024) {
      const int node = s >> 2;
      sy4w[yslot(node, s & 3)] = (node < NN) ? ysrc[s] : z4;
    }
    const uint4* __restrict__ esrc = (const uint4*)(ell_g + (size_t)b * ELLB);
    uint4* ed = (uint4*)s_ell;
    for (int s = tid; s < ELLB / 8; s += 1024) ed[s] = esrc[s];
    for (int i = tid; i <= NT16; i += 1024) s_elloff[i] = elloff_g[(size_t)b * (NT16 + 1) + i];
    for (int i = tid; i < NN; i += 1024) s_dv[i] = dinv[(size_t)b * NN + i];
    if (tid == 1023) s_dv[NN] = 0.f;
  }
  u16 pvs[3];
#pragma unroll
  for (int p = 0; p < 3; ++p) {
    const int t = p * 16 + wv;
    pvs[p] = (t < NT16) ? perm_g[(size_t)b * NPAD + t * 16 + col] : (u16)0xFFFF;
  }
  const u16 pvt = (tid < NPAD) ? perm_g[(size_t)b * NPAD + tid] : (u16)0xFFFF;

  union { u32 u[4]; short8 v; } uaA0, uaA1, uaB0, uaB1;
#pragma unroll
  for (int jj = 0; jj < 4; ++jj) {
    uaA0.u[jj] = pack2(W2[(kg * 8 + 2 * jj) * CH + col],      W2[(kg * 8 + 2 * jj + 1) * CH + col]);
    uaA1.u[jj] = pack2(W2[(kg * 8 + 2 * jj) * CH + 16 + col], W2[(kg * 8 + 2 * jj + 1) * CH + 16 + col]);
    uaB0.u[jj] = pack2(W3[(kg * 8 + 2 * jj) * CH + col],      W3[(kg * 8 + 2 * jj + 1) * CH + col]);
    uaB1.u[jj] = pack2(W3[(kg * 8 + 2 * jj) * CH + 16 + col], W3[(kg * 8 + 2 * jj + 1) * CH + 16 + col]);
  }
  float b1r[8], b2r[8], b3r[8], w4r[8];
#pragma unroll
  for (int j = 0; j < 8; ++j) {
    b1r[j] = b1[kg * 8 + j];
    b2r[j] = b2[kg * 8 + j];
    b3r[j] = b3[kg * 8 + j];
    w4r[j] = W4[kg * 8 + j];
  }
  const float bb4 = b4[0];
  __syncthreads();

  gcn_pass32<0>(s_y, s_ell, s_elloff, s_dv, pvs, wv, col, kg, uaA0.v, uaA1.v, b1r);
  gcn_pass32<1>(s_y, s_ell, s_elloff, s_dv, pvs, wv, col, kg, uaB0.v, uaB1.v, b2r);

  // layer 4: agg + b3, lrelu+t, dot W4 (32->1), *dinv -> s_h
  {
    const uint4* sy4 = (const uint4*)s_y;
    const f16x2 hz = {(_Float16)0, (_Float16)0};
#pragma unroll
    for (int p = 0; p < 3; ++p) {
      const int t = p * 16 + wv;
      const int pv = (t < NT16) ? (int)pvs[p] : 0xFFFF;
      const int node = (pv == 0xFFFF) ? NN : pv;
      int base = 0, md4 = 0;
      if (t < NT16) { base = s_elloff[t]; md4 = s_elloff[t + 1] - base; }
      base = __builtin_amdgcn_readfirstlane(base);
      md4 = __builtin_amdgcn_readfirstlane(md4);
      f16x2 a0h, a1h, a2h, a3h;
      f16x2 b0h = hz, b1h = hz, b2h = hz, b3h = hz;
      {
        uint4 u = sy4[yslot(node, kg)];
        a0h = u2h(u.x); a1h = u2h(u.y); a2h = u2h(u.z); a3h = u2h(u.w);
      }
      float zx[8];
#pragma unroll
      for (int j = 0; j < 8; ++j) zx[j] = 0.f;
      const u16* ep = s_ell + base * 16 + col;
      AGG_LOOP(ep)
      const float dv = s_dv[node];
      float part = 0.f;
#pragma unroll
      for (int j = 0; j < 8; ++j) {
        float t2 = fmaf(dv, zx[j], b3r[j]);
        float l = (t2 > 0.f) ? t2 : 0.01f * t2;
        part = fmaf(l + t2, w4r[j], part);
      }
      part += __shfl_xor(part, 16, 64);
      part += __shfl_xor(part, 32, 64);
      if (pv != 0xFFFF && kg == 0) s_h[node] = part * dv;
    }
  }
  __syncthreads();
  if (tid == 1023) s_h[NN] = 0.f;
  __syncthreads();

  // tail aggregation via ELL: z = h[node] + sum h[e0>>2]; lrelu(dinv*z + b4)
  {
    float hval = 0.f;
    int node = -1;
    if (tid < NPAD && pvt != 0xFFFF) {
      node = (int)pvt;
      const int t = tid >> 4, c = tid & 15;
      const int base = s_elloff[t], md4 = s_elloff[t + 1] - base;
      float z = s_h[node];
      const u16* ep = s_ell + base * 16 + c;
      for (int kk = 0; kk < md4; ++kk) z += s_h[((int)ep[kk * 16]) >> 2];
      float t2 = fmaf(s_dv[node], z, bb4);
      hval = (t2 > 0.f) ? t2 : 0.01f * t2;
    }
    __syncthreads();
    if (node >= 0) s_h[node] = hval;
  }
  __syncthreads();

  // FC1: 714 -> 128, 8-way split-K
  const int j = tid & 127, q = tid >> 7;
  {
    const int n0 = (q * NN) >> 3, n1 = ((q + 1) * NN) >> 3;
    const float* __restrict__ w = Wf1 + j;
    float a0 = 0.f, a1 = 0.f;
    int n = n0;
#pragma unroll 4
    for (; n + 2 <= n1; n += 2) {
      a0 = fmaf(s_h[n], w[(size_t)n * 128], a0);
      a1 = fmaf(s_h[n + 1], w[(size_t)(n + 1) * 128], a1);
    }
    if (n < n1) a0 = fmaf(s_h[n], w[(size_t)n * 128], a0);
    s_red[tid] = a0 + a1;
  }
  __syncthreads();
  if (tid < 128) {
    float v = bf1[tid];
#pragma unroll
    for (int m = 0; m < 8; ++m) v += s_red[tid + 128 * m];
    s_u[tid] = fmaxf(v, 0.f);
  }
  __syncthreads();
  // FC2: 128 -> 128, 8-way split-K
  {
    const float* __restrict__ w = Wf2 + j;
    float a0 = 0.f, a1 = 0.f;
#pragma unroll
    for (int k = q * 16; k < q * 16 + 16; k += 2) {
      a0 = fmaf(s_u[k], w[(size_t)k * 128], a0);
      a1 = fmaf(s_u[k + 1], w[(size_t)(k + 1) * 128], a1);
    }
    s_red[tid] = a0 + a1;
  }
  __syncthreads();
  if (tid < 128) {
    float v = bf2[tid];
#pragma unroll
    for (int m = 0; m < 8; ++m) v += s_red[tid + 128 * m];
    out[(size_t)b * 128 + tid] = fmaxf(v, 0.f);
  }
}

extern "C" void kernel_launch(void* const* d_in, const int* in_sizes, int n_in,
                              void* d_out, int out_size, void* d_ws, size_t ws_size,
                              hipStream_t stream)
{
  (void)in_sizes; (void)n_in; (void)out_size; (void)ws_size;
  const int*   ids  = (const int*)d_in[0];
  const float* cont = (const float*)d_in[1];
  const int*   edges= (const int*)d_in[2];
  const float* emb  = (const float*)d_in[3];
  const float* W1   = (const float*)d_in[4];
  const float* b1   = (const float*)d_in[5];
  const float* W2   = (const float*)d_in[6];
  const float* b2   = (const float*)d_in[7];
  const float* W3   = (const float*)d_in[8];
  const float* b3   = (const float*)d_in[9];
  const float* W4   = (const float*)d_in[10];
  const float* b4   = (const float*)d_in[11];
  const float* Wf1  = (const float*)d_in[12];
  const float* bf1  = (const float*)d_in[13];
  const float* Wf2  = (const float*)d_in[14];
  const float* bf2  = (const float*)d_in[15];
  float* out = (float*)d_out;

  char* ws = (char*)d_ws;
  size_t off = 0;
  auto alloc = [&](size_t bytes) -> void* {
    void* p = ws + off;
    off = (off + bytes + 255) & ~(size_t)255;
    return p;
  };
  float* dinv     = (float*)alloc((size_t)BB * NN * 4);
  u16*   perm     = (u16*)  alloc((size_t)BB * NPAD * 2);
  u16*   ell      = (u16*)  alloc((size_t)BB * ELLB * 2);
  u16*   elloff   = (u16*)  alloc((size_t)BB * (NT16 + 1) * 2);
  u16*   T        = (u16*)  alloc((size_t)2 * VOCAB * 32 * 2);  // fp16 [2][VOCAB][32]
  u32*   yA       = (u32*)  alloc((size_t)BB * NN * 16 * 4);

  hipLaunchKernelGGL(k_setup, dim3(NPRE + BB), dim3(256), 0, stream,
                     emb, W1, T, edges, dinv, perm, ell, elloff);
  hipLaunchKernelGGL(k_gcn1v, dim3((BB * NN) / 256), dim3(256), 0, stream,
                     ids, cont, T, W1, dinv, yA);
  hipLaunchKernelGGL(k_fused, dim3(BB), dim3(1024), 0, stream,
                     yA, dinv, perm, ell, elloff,
                     b1, W2, b2, W3, b3, W4, b4, Wf1, bf1, Wf2, bf2, out);
}

// Round 20
// 99.920 us; speedup vs baseline: 1.1611x; 1.1611x over previous
//
#include <hip/hip_runtime.h>
#include <hip/hip_bf16.h>

#define BB 512
#define NN 714
#define EE 4096
#define ED2 62
#define CH 32
#define NT16 45    // ceil(NN/16)
#define NPAD 720   // NT16*16
#define VOCAB 38733
#define NPRE 303   // ceil(VOCAB/128) blocks for MFMA emb@W1 precompute
#define ELLR 432   // ELL row capacity (rows of 16 u16), rows per tile padded to x4
#define ELLB (ELLR*16)

typedef unsigned int u32;
typedef unsigned short u16;
typedef short short8 __attribute__((ext_vector_type(8)));
typedef float float4v __attribute__((ext_vector_type(4)));
typedef _Float16 f16x2 __attribute__((ext_vector_type(2)));
typedef __fp16 fp16x2 __attribute__((ext_vector_type(2)));

__device__ __forceinline__ u32 f2bf(float f) {
  u32 u = __float_as_uint(f);
  return (u + 0x7fffu + ((u >> 16) & 1u)) >> 16;
}
__device__ __forceinline__ u32 pack2(float a, float b) {
  return f2bf(a) | (f2bf(b) << 16);
}
__device__ __forceinline__ f16x2 u2h(u32 x) { union { u32 u; f16x2 h; } c; c.u = x; return c.h; }
__device__ __forceinline__ u32 packh(float a, float b) {
  union { fp16x2 h; u32 u; } c;
  c.h = __builtin_amdgcn_cvt_pkrtz(a, b);
  return c.u;
}

// y-in-LDS swizzle: uint4 slot q of node -> q ^ ((node>>1)&3).
__device__ __forceinline__ int yslot(int node, int q) {
  return (node << 2) | (q ^ ((node >> 1) & 3));
}

// ---------------- Fused setup kernel ----------------
// blocks [0, NPRE): T = emb @ [W1_0 | W1_1] via MFMA -> fp16 [VOCAB][64] (32 u32/row)
// blocks [NPRE, NPRE+BB): per-batch degree/dinv/perm/ELL prep
__global__ __launch_bounds__(256) void k_setup(const float* __restrict__ emb,
    const float* __restrict__ W1, u32* __restrict__ Tg,
    const int* __restrict__ edges,
    float* __restrict__ dinv, u16* __restrict__ perm_g,
    u16* __restrict__ ell_g, u16* __restrict__ elloff_g)
{
  const int tid = threadIdx.x;
  if (blockIdx.x < NPRE) {
    const int base = blockIdx.x * 128;
    const int lane = tid & 63, wv = tid >> 6;
    const int col = lane & 15, kg = lane >> 4;
    __shared__ __align__(16) unsigned short sX[128 * 64];   // 16 KB bf16 tile
    // stage 128 contiguous emb rows as bf16 (cols 62,63 = 0), chunk-XOR swizzle
    for (int s = tid; s < 1024; s += 256) {
      const int row = s >> 3, ck = s & 7;
      uint4 w = {0, 0, 0, 0};
      if (base + row < VOCAB) {
        const float2* __restrict__ p = (const float2*)(emb + (size_t)(base + row) * ED2 + ck * 8);
        float2 v0 = p[0], v1 = p[1], v2 = p[2];
        float2 v3; v3.x = 0.f; v3.y = 0.f;
        if (ck != 7) v3 = p[3];
        w.x = pack2(v0.x, v0.y); w.y = pack2(v1.x, v1.y);
        w.z = pack2(v2.x, v2.y); w.w = pack2(v3.x, v3.y);
      }
      ((uint4*)sX)[(row * 8 + ck) ^ (row & 7)] = w;
    }
    // A fragments: hh 0,1 -> tbl0 (W1 rows 0..61), hh 2,3 -> tbl1 (W1 rows 62..123)
    union { u32 u[4]; short8 v; } A[2][4];
#pragma unroll
    for (int kc = 0; kc < 2; ++kc)
#pragma unroll
      for (int hh = 0; hh < 4; ++hh) {
        const int tbl = hh >> 1;
        const int ch = ((hh & 1) * 16) + col;
#pragma unroll
        for (int jj = 0; jj < 4; ++jj) {
          const int k0 = kc * 32 + kg * 8 + 2 * jj;
          const int k1 = k0 + 1;
          const float wa = (k0 < 62) ? W1[(tbl * 62 + k0) * CH + ch] : 0.f;
          const float wb = (k1 < 62) ? W1[(tbl * 62 + k1) * CH + ch] : 0.f;
          A[kc][hh].u[jj] = pack2(wa, wb);
        }
      }
    __syncthreads();
    for (int t = wv; t < 8; t += 4) {
      const int ln = t * 16 + col;
      float4v acc[4];
#pragma unroll
      for (int hh = 0; hh < 4; ++hh) { acc[hh][0] = 0.f; acc[hh][1] = 0.f; acc[hh][2] = 0.f; acc[hh][3] = 0.f; }
#pragma unroll
      for (int kc = 0; kc < 2; ++kc) {
        const int idx8 = (ln * 8 + kc * 4 + kg) ^ (ln & 7);
        short8 bf = *(const short8*)(sX + idx8 * 8);
#pragma unroll
        for (int hh = 0; hh < 4; ++hh)
          acc[hh] = __builtin_amdgcn_mfma_f32_16x16x32_bf16(A[kc][hh].v, bf, acc[hh], 0, 0, 0);
      }
      const int row = base + ln;
      if (row < VOCAB) {
        u32* op = Tg + (size_t)row * 32;
#pragma unroll
        for (int hh = 0; hh < 4; ++hh) {
          uint2 s0 = { packh(acc[hh][0], acc[hh][1]), packh(acc[hh][2], acc[hh][3]) };
          *(uint2*)(op + hh * 8 + 2 * kg) = s0;
        }
      }
    }
    return;
  }
  const int b = blockIdx.x - NPRE;
  const int* __restrict__ er = edges + (size_t)b * 2 * EE;       // e[0] = source (row)
  const int* __restrict__ ec = er + EE;                          // e[1] = target (col)
  __shared__ int s_cnt[NN];
  __shared__ int s_a[1024];
  __shared__ int s_b[1024];
  __shared__ u16 s_rows16[EE];
  __shared__ u16 s_perm[NPAD];
  __shared__ u16 s_degP[NPAD];
  __shared__ int s_hist[64];
  __shared__ int s_md[NT16 + 1];

  for (int i = tid; i < NN; i += 256) s_cnt[i] = 0;
  __syncthreads();
  for (int e = tid; e < EE; e += 256) atomicAdd(&s_cnt[ec[e]], 1);
  __syncthreads();
  for (int i = tid; i < 1024; i += 256) s_a[i] = (i < NN) ? s_cnt[i] : 0;
  for (int i = tid; i < NN; i += 256)
    dinv[(size_t)b * NN + i] = rsqrtf((float)(s_cnt[i] + 1));    // +1 self loop
  __syncthreads();
  int* src = s_a; int* dst = s_b;
  for (int d = 1; d < 1024; d <<= 1) {
    for (int i = tid; i < 1024; i += 256) {
      int v = src[i];
      if (i >= d) v += src[i - d];
      dst[i] = v;
    }
    __syncthreads();
    int* t = src; src = dst; dst = t;
  }
  // src (= s_a, 10 swaps) = inclusive scan of degree counts
  for (int i = tid; i < NN; i += 256) s_cnt[i] = 0;  // fill cursors
  __syncthreads();
  for (int e = tid; e < EE; e += 256) {
    int c = ec[e];
    int p = atomicAdd(&s_cnt[c], 1);
    int base = (c == 0) ? 0 : src[c - 1];
    s_rows16[base + p] = (u16)er[e];
  }
  // degree-sorted perm (counting sort, 64 bins)
  for (int i = tid; i < 64; i += 256) s_hist[i] = 0;
  for (int i = tid; i < NPAD; i += 256) { s_perm[i] = 0xFFFFu; s_degP[i] = 0; }
  __syncthreads();
  for (int i = tid; i < NN; i += 256) {
    int deg = src[i] - (i ? src[i - 1] : 0);
    atomicAdd(&s_hist[deg < 63 ? deg : 63], 1);
  }
  __syncthreads();
  // wave-parallel exclusive scan of the 64 histogram bins
  if (tid < 64) {
    int v = s_hist[tid];
    int incl = v;
#pragma unroll
    for (int d = 1; d < 64; d <<= 1) {
      int o = __shfl_up(incl, d, 64);
      if (tid >= d) incl += o;
    }
    s_hist[tid] = incl - v;
  }
  __syncthreads();
  for (int i = tid; i < NN; i += 256) {
    int deg = src[i] - (i ? src[i - 1] : 0);
    int pos = atomicAdd(&s_hist[deg < 63 ? deg : 63], 1);
    s_perm[pos] = (u16)i;
    s_degP[pos] = (u16)deg;
  }
  __syncthreads();
  for (int i = tid; i < NPAD; i += 256) perm_g[(size_t)b * NPAD + i] = s_perm[i];
  // per-tile max degree, padded to multiple of 4
  if (tid < NT16) {
    int md = 0;
#pragma unroll
    for (int c = 0; c < 16; ++c) { int d = s_degP[tid * 16 + c]; md = d > md ? d : md; }
    s_md[tid] = (md + 3) & ~3;
  }
  __syncthreads();
  // wave-parallel exclusive scan of the 45 tile sizes (clamped to ELLR)
  if (tid < 64) {
    int m = (tid < NT16) ? s_md[tid] : 0;
    int incl = m;
#pragma unroll
    for (int d = 1; d < 64; d <<= 1) {
      int o = __shfl_up(incl, d, 64);
      if (tid >= d) incl += o;
    }
    int excl = incl - m;
    if (excl > ELLR) excl = ELLR;
    if (tid < NT16) s_md[tid] = excl;
    if (tid == NT16 - 1) s_md[NT16] = (incl > ELLR) ? ELLR : incl;
  }
  __syncthreads();
  if (tid <= NT16) elloff_g[(size_t)b * (NT16 + 1) + tid] = (u16)s_md[tid];
  // fill ELL per-wave (wave w takes tiles w, w+4, ...), PRE-SWIZZLED entries (pad -> dummy NN)
  {
    const int wv4 = tid >> 6, lane = tid & 63;
    u16* eg = ell_g + (size_t)b * ELLB;
    for (int t = wv4; t < NT16; t += 4) {
      const int base = s_md[t], md4 = s_md[t + 1] - base;
      for (int s = lane; s < md4 * 16; s += 64) {
        const int kk = s >> 4, col = s & 15;
        const int pv = s_perm[t * 16 + col];
        int r = NN;
        if (pv != 0xFFFF) {
          const int deg = s_degP[t * 16 + col];
          if (kk < deg) {
            const int off = pv ? src[pv - 1] : 0;
            r = (int)s_rows16[off + kk];
          }
        }
        eg[base * 16 + s] = (u16)((r << 2) | ((r >> 1) & 3));
      }
    }
  }
}

// ---------------- Kernel B: GCN1 via precomputed table: y1 = dinv*(T[id0].lo + T[id1].hi + cont@Wc) ----------------
__global__ __launch_bounds__(256) void k_gcn1v(
    const int* __restrict__ ids, const float* __restrict__ cont,
    const u32* __restrict__ T, const float* __restrict__ W1,
    const float* __restrict__ dinv, u32* __restrict__ y1)
{
  const int idx = blockIdx.x * 256 + threadIdx.x;   // BB*NN = 1428*256 exactly
  __shared__ float sWc[96];
  if (threadIdx.x < 96) sWc[threadIdx.x] = W1[124 * 32 + threadIdx.x];
  __syncthreads();
  const int2 id2 = ((const int2*)ids)[idx];
  const uint4* __restrict__ t0 = (const uint4*)(T + (size_t)id2.x * 32);        // ch 0..31
  const uint4* __restrict__ t1 = (const uint4*)(T + (size_t)id2.y * 32 + 16);   // ch 32..63
  uint4 q0 = t0[0], q1 = t0[1], q2 = t0[2], q3 = t0[3];
  uint4 r0 = t1[0], r1 = t1[1], r2 = t1[2], r3 = t1[3];
  const float* __restrict__ c3 = cont + (size_t)idx * 3;
  const float c0 = c3[0], c1 = c3[1], c2 = c3[2];
  const float dv = dinv[idx];
  const u32 qs[16] = { q0.x, q0.y, q0.z, q0.w, q1.x, q1.y, q1.z, q1.w,
                       q2.x, q2.y, q2.z, q2.w, q3.x, q3.y, q3.z, q3.w };
  const u32 rs[16] = { r0.x, r0.y, r0.z, r0.w, r1.x, r1.y, r1.z, r1.w,
                       r2.x, r2.y, r2.z, r2.w, r3.x, r3.y, r3.z, r3.w };
  u32 os[16];
#pragma unroll
  for (int s = 0; s < 16; ++s) {
    f16x2 a = u2h(qs[s]);
    f16x2 bb = u2h(rs[s]);
    const int ch = 2 * s;
    float v0 = (float)a.x + (float)bb.x;
    float v1 = (float)a.y + (float)bb.y;
    v0 = fmaf(c0, sWc[ch],      v0);
    v1 = fmaf(c0, sWc[ch + 1],  v1);
    v0 = fmaf(c1, sWc[32 + ch],     v0);
    v1 = fmaf(c1, sWc[32 + ch + 1], v1);
    v0 = fmaf(c2, sWc[64 + ch],     v0);
    v1 = fmaf(c2, sWc[64 + ch + 1], v1);
    os[s] = packh(v0 * dv, v1 * dv);
  }
  uint4* op = (uint4*)(y1 + (size_t)idx * 16);
#pragma unroll
  for (int s4 = 0; s4 < 4; ++s4) {
    uint4 w = { os[4 * s4], os[4 * s4 + 1], os[4 * s4 + 2], os[4 * s4 + 3] };
    op[s4] = w;
  }
}

// ---------------- Fused kernel: layers 2,3,4 + tail ----------------
#define EDGEA(EP, K) { const int a16 = ((int)(EP)[(K) * 16]) ^ kg; \
  uint4 n = sy4[a16]; \
  a0h += u2h(n.x); a1h += u2h(n.y); a2h += u2h(n.z); a3h += u2h(n.w); }
#define EDGEB(EP, K) { const int a16 = ((int)(EP)[(K) * 16]) ^ kg; \
  uint4 n = sy4[a16]; \
  b0h += u2h(n.x); b1h += u2h(n.y); b2h += u2h(n.z); b3h += u2h(n.w); }
#define FLUSH { a0h += b0h; a1h += b1h; a2h += b2h; a3h += b3h; \
  zx[0] += (float)a0h.x; zx[1] += (float)a0h.y; \
  zx[2] += (float)a1h.x; zx[3] += (float)a1h.y; \
  zx[4] += (float)a2h.x; zx[5] += (float)a2h.y; \
  zx[6] += (float)a3h.x; zx[7] += (float)a3h.y; \
  a0h = hz; a1h = hz; a2h = hz; a3h = hz; \
  b0h = hz; b1h = hz; b2h = hz; b3h = hz; }
#define AGG_LOOP(EP) { int kk = 0; \
  while (kk + 16 <= md4) { \
    _Pragma("unroll") for (int e = 0; e < 16; e += 2) { EDGEA(EP, kk + e) EDGEB(EP, kk + e + 1) } \
    FLUSH \
    kk += 16; } \
  if (kk + 8 <= md4) { \
    _Pragma("unroll") for (int e = 0; e < 8; e += 2) { EDGEA(EP, kk + e) EDGEB(EP, kk + e + 1) } \
    FLUSH \
    kk += 8; } \
  if (kk < md4) { \
    _Pragma("unroll") for (int e = 0; e < 4; e += 2) { EDGEA(EP, kk + e) EDGEB(EP, kk + e + 1) } \
    FLUSH } }

template<int ACT>
__device__ __forceinline__ void gcn_pass32(
    u32* __restrict__ sy, const u16* __restrict__ s_ell,
    const u16* __restrict__ s_elloff, const float* __restrict__ s_dv,
    const u16* __restrict__ pvs,
    const int wv, const int col, const int kg,
    const short8 a0v, const short8 a1v, const float* __restrict__ bias8)
{
  const uint4* sy4 = (const uint4*)sy;
  const f16x2 hz = {(_Float16)0, (_Float16)0};
  u32 outs[3][4];
  int nodes[3];
#pragma unroll
  for (int p = 0; p < 3; ++p) {
    const int t = p * 16 + wv;
    const int pv = (t < NT16) ? (int)pvs[p] : 0xFFFF;
    const int node = (pv == 0xFFFF) ? NN : pv;
    nodes[p] = (pv == 0xFFFF) ? -1 : pv;
    int base = 0, md4 = 0;
    if (t < NT16) { base = s_elloff[t]; md4 = s_elloff[t + 1] - base; }
    base = __builtin_amdgcn_readfirstlane(base);
    md4 = __builtin_amdgcn_readfirstlane(md4);
    f16x2 a0h, a1h, a2h, a3h;
    f16x2 b0h = hz, b1h = hz, b2h = hz, b3h = hz;
    {
      uint4 u = sy4[yslot(node, kg)];          // self (dummy row = zeros)
      a0h = u2h(u.x); a1h = u2h(u.y); a2h = u2h(u.z); a3h = u2h(u.w);
    }
    float zx[8];
#pragma unroll
    for (int j = 0; j < 8; ++j) zx[j] = 0.f;
    const u16* ep = s_ell + base * 16 + col;
    AGG_LOOP(ep)
    const float dv = s_dv[node];               // dummy dv = 0
    float h[8];
#pragma unroll
    for (int j = 0; j < 8; ++j) {
      float t2 = fmaf(dv, zx[j], bias8[j]);
      float l = (t2 > 0.f) ? t2 : 0.01f * t2;
      h[j] = (ACT == 0) ? l : (l + t2);
    }
    union { u32 u[4]; short8 v; } ub;
#pragma unroll
    for (int jj = 0; jj < 4; ++jj) ub.u[jj] = pack2(h[2 * jj], h[2 * jj + 1]);
    float4v z4 = {0.f, 0.f, 0.f, 0.f};
    float4v d0 = __builtin_amdgcn_mfma_f32_16x16x32_bf16(a0v, ub.v, z4, 0, 0, 0);
    float4v d1 = __builtin_amdgcn_mfma_f32_16x16x32_bf16(a1v, ub.v, z4, 0, 0, 0);
    outs[p][0] = packh(d0[0] * dv, d0[1] * dv);
    outs[p][1] = packh(d0[2] * dv, d0[3] * dv);
    outs[p][2] = packh(d1[0] * dv, d1[1] * dv);
    outs[p][3] = packh(d1[2] * dv, d1[3] * dv);
  }
  __syncthreads();
#pragma unroll
  for (int p = 0; p < 3; ++p) {
    const int node = nodes[p];
    if (node >= 0) {
      const int sw = (node >> 1) & 3;
      u32* op = sy + node * 16;
      uint2 s0 = { outs[p][0], outs[p][1] };
      uint2 s1 = { outs[p][2], outs[p][3] };
      *(uint2*)(op + (((kg >> 1) ^ sw) << 2) + ((2 * kg) & 3)) = s0;
      *(uint2*)(op + (((2 + (kg >> 1)) ^ sw) << 2) + ((2 * kg) & 3)) = s1;
    }
  }
  __syncthreads();
}

__global__ __launch_bounds__(1024) void k_fused(
    const u32* __restrict__ yin, const float* __restrict__ dinv,
    const u16* __restrict__ perm_g, const u16* __restrict__ ell_g,
    const u16* __restrict__ elloff_g,
    const float* __restrict__ b1, const float* __restrict__ W2,
    const float* __restrict__ b2, const float* __restrict__ W3,
    const float* __restrict__ b3, const float* __restrict__ W4,
    const float* __restrict__ b4, const float* __restrict__ Wf1,
    const float* __restrict__ bf1, const float* __restrict__ Wf2,
    const float* __restrict__ bf2, float* __restrict__ out)
{
  const int b = blockIdx.x;
  const int tid = threadIdx.x;
  const int lane = tid & 63;
  const int wv = tid >> 6;          // wave 0..15
  const int col = lane & 15;
  const int kg = lane >> 4;

  __shared__ __align__(16) char smem[65408];
  u32*   s_y      = (u32*)smem;                     // 45760 B (715 rows; dead later)
  u16*   s_ell    = (u16*)(smem + 45760);           // 13824
  u16*   s_elloff = (u16*)(smem + 59584);           // 96
  float* s_dv     = (float*)(smem + 59680);         // 2864 (incl dummy)
  float* s_h      = (float*)(smem + 62544);         // 2864 (incl dummy)
  float* s_red    = (float*)smem;                   // aliases dead s_y
  float* s_u      = (float*)(smem + 8192);          // aliases dead s_y

  {
    const uint4* __restrict__ ysrc = (const uint4*)(yin + (size_t)b * NN * 16);
    uint4* sy4w = (uint4*)s_y;
    const uint4 z4 = {0, 0, 0, 0};
    for (int s = tid; s < (NN + 1) * 4; s += 1024) {
      const int node = s >> 2;
      sy4w[yslot(node, s & 3)] = (node < NN) ? ysrc[s] : z4;
    }
    const uint4* __restrict__ esrc = (const uint4*)(ell_g + (size_t)b * ELLB);
    uint4* ed = (uint4*)s_ell;
    for (int s = tid; s < ELLB / 8; s += 1024) ed[s] = esrc[s];
    for (int i = tid; i <= NT16; i += 1024) s_elloff[i] = elloff_g[(size_t)b * (NT16 + 1) + i];
    for (int i = tid; i < NN; i += 1024) s_dv[i] = dinv[(size_t)b * NN + i];
    if (tid == 1023) s_dv[NN] = 0.f;
  }
  u16 pvs[3];
#pragma unroll
  for (int p = 0; p < 3; ++p) {
    const int t = p * 16 + wv;
    pvs[p] = (t < NT16) ? perm_g[(size_t)b * NPAD + t * 16 + col] : (u16)0xFFFF;
  }
  const u16 pvt = (tid < NPAD) ? perm_g[(size_t)b * NPAD + tid] : (u16)0xFFFF;

  union { u32 u[4]; short8 v; } uaA0, uaA1, uaB0, uaB1;
#pragma unroll
  for (int jj = 0; jj < 4; ++jj) {
    uaA0.u[jj] = pack2(W2[(kg * 8 + 2 * jj) * CH + col],      W2[(kg * 8 + 2 * jj + 1) * CH + col]);
    uaA1.u[jj] = pack2(W2[(kg * 8 + 2 * jj) * CH + 16 + col], W2[(kg * 8 + 2 * jj + 1) * CH + 16 + col]);
    uaB0.u[jj] = pack2(W3[(kg * 8 + 2 * jj) * CH + col],      W3[(kg * 8 + 2 * jj + 1) * CH + col]);
    uaB1.u[jj] = pack2(W3[(kg * 8 + 2 * jj) * CH + 16 + col], W3[(kg * 8 + 2 * jj + 1) * CH + 16 + col]);
  }
  float b1r[8], b2r[8], b3r[8], w4r[8];
#pragma unroll
  for (int j = 0; j < 8; ++j) {
    b1r[j] = b1[kg * 8 + j];
    b2r[j] = b2[kg * 8 + j];
    b3r[j] = b3[kg * 8 + j];
    w4r[j] = W4[kg * 8 + j];
  }
  const float bb4 = b4[0];
  __syncthreads();

  gcn_pass32<0>(s_y, s_ell, s_elloff, s_dv, pvs, wv, col, kg, uaA0.v, uaA1.v, b1r);
  gcn_pass32<1>(s_y, s_ell, s_elloff, s_dv, pvs, wv, col, kg, uaB0.v, uaB1.v, b2r);

  // layer 4: agg + b3, lrelu+t, dot W4 (32->1), *dinv -> s_h
  {
    const uint4* sy4 = (const uint4*)s_y;
    const f16x2 hz = {(_Float16)0, (_Float16)0};
#pragma unroll
    for (int p = 0; p < 3; ++p) {
      const int t = p * 16 + wv;
      const int pv = (t < NT16) ? (int)pvs[p] : 0xFFFF;
      const int node = (pv == 0xFFFF) ? NN : pv;
      int base = 0, md4 = 0;
      if (t < NT16) { base = s_elloff[t]; md4 = s_elloff[t + 1] - base; }
      base = __builtin_amdgcn_readfirstlane(base);
      md4 = __builtin_amdgcn_readfirstlane(md4);
      f16x2 a0h, a1h, a2h, a3h;
      f16x2 b0h = hz, b1h = hz, b2h = hz, b3h = hz;
      {
        uint4 u = sy4[yslot(node, kg)];
        a0h = u2h(u.x); a1h = u2h(u.y); a2h = u2h(u.z); a3h = u2h(u.w);
      }
      float zx[8];
#pragma unroll
      for (int j = 0; j < 8; ++j) zx[j] = 0.f;
      const u16* ep = s_ell + base * 16 + col;
      AGG_LOOP(ep)
      const float dv = s_dv[node];
      float part = 0.f;
#pragma unroll
      for (int j = 0; j < 8; ++j) {
        float t2 = fmaf(dv, zx[j], b3r[j]);
        float l = (t2 > 0.f) ? t2 : 0.01f * t2;
        part = fmaf(l + t2, w4r[j], part);
      }
      part += __shfl_xor(part, 16, 64);
      part += __shfl_xor(part, 32, 64);
      if (pv != 0xFFFF && kg == 0) s_h[node] = part * dv;
    }
  }
  __syncthreads();
  if (tid == 1023) s_h[NN] = 0.f;
  __syncthreads();

  // tail aggregation via ELL: z = h[node] + sum h[e0>>2]; lrelu(dinv*z + b4)
  {
    float hval = 0.f;
    int node = -1;
    if (tid < NPAD && pvt != 0xFFFF) {
      node = (int)pvt;
      const int t = tid >> 4, c = tid & 15;
      const int base = s_elloff[t], md4 = s_elloff[t + 1] - base;
      float z = s_h[node];
      const u16* ep = s_ell + base * 16 + c;
      for (int kk = 0; kk < md4; ++kk) z += s_h[((int)ep[kk * 16]) >> 2];
      float t2 = fmaf(s_dv[node], z, bb4);
      hval = (t2 > 0.f) ? t2 : 0.01f * t2;
    }
    __syncthreads();
    if (node >= 0) s_h[node] = hval;
  }
  __syncthreads();

  // FC1: 714 -> 128, 8-way split-K
  const int j = tid & 127, q = tid >> 7;
  {
    const int n0 = (q * NN) >> 3, n1 = ((q + 1) * NN) >> 3;
    const float* __restrict__ w = Wf1 + j;
    float a0 = 0.f, a1 = 0.f;
    int n = n0;
#pragma unroll 4
    for (; n + 2 <= n1; n += 2) {
      a0 = fmaf(s_h[n], w[(size_t)n * 128], a0);
      a1 = fmaf(s_h[n + 1], w[(size_t)(n + 1) * 128], a1);
    }
    if (n < n1) a0 = fmaf(s_h[n], w[(size_t)n * 128], a0);
    s_red[tid] = a0 + a1;
  }
  __syncthreads();
  if (tid < 128) {
    float v = bf1[tid];
#pragma unroll
    for (int m = 0; m < 8; ++m) v += s_red[tid + 128 * m];
    s_u[tid] = fmaxf(v, 0.f);
  }
  __syncthreads();
  // FC2: 128 -> 128, 8-way split-K
  {
    const float* __restrict__ w = Wf2 + j;
    float a0 = 0.f, a1 = 0.f;
#pragma unroll
    for (int k = q * 16; k < q * 16 + 16; k += 2) {
      a0 = fmaf(s_u[k], w[(size_t)k * 128], a0);
      a1 = fmaf(s_u[k + 1], w[(size_t)(k + 1) * 128], a1);
    }
    s_red[tid] = a0 + a1;
  }
  __syncthreads();
  if (tid < 128) {
    float v = bf2[tid];
#pragma unroll
    for (int m = 0; m < 8; ++m) v += s_red[tid + 128 * m];
    out[(size_t)b * 128 + tid] = fmaxf(v, 0.f);
  }
}

extern "C" void kernel_launch(void* const* d_in, const int* in_sizes, int n_in,
                              void* d_out, int out_size, void* d_ws, size_t ws_size,
                              hipStream_t stream)
{
  (void)in_sizes; (void)n_in; (void)out_size; (void)ws_size;
  const int*   ids  = (const int*)d_in[0];
  const float* cont = (const float*)d_in[1];
  const int*   edges= (const int*)d_in[2];
  const float* emb  = (const float*)d_in[3];
  const float* W1   = (const float*)d_in[4];
  const float* b1   = (const float*)d_in[5];
  const float* W2   = (const float*)d_in[6];
  const float* b2   = (const float*)d_in[7];
  const float* W3   = (const float*)d_in[8];
  const float* b3   = (const float*)d_in[9];
  const float* W4   = (const float*)d_in[10];
  const float* b4   = (const float*)d_in[11];
  const float* Wf1  = (const float*)d_in[12];
  const float* bf1  = (const float*)d_in[13];
  const float* Wf2  = (const float*)d_in[14];
  const float* bf2  = (const float*)d_in[15];
  float* out = (float*)d_out;

  char* ws = (char*)d_ws;
  size_t off = 0;
  auto alloc = [&](size_t bytes) -> void* {
    void* p = ws + off;
    off = (off + bytes + 255) & ~(size_t)255;
    return p;
  };
  float* dinv     = (float*)alloc((size_t)BB * NN * 4);
  u16*   perm     = (u16*)  alloc((size_t)BB * NPAD * 2);
  u16*   ell      = (u16*)  alloc((size_t)BB * ELLB * 2);
  u16*   elloff   = (u16*)  alloc((size_t)BB * (NT16 + 1) * 2);
  u32*   T        = (u32*)  alloc((size_t)VOCAB * 32 * 4);   // fp16 [VOCAB][64]
  u32*   yA       = (u32*)  alloc((size_t)BB * NN * 16 * 4);

  hipLaunchKernelGGL(k_setup, dim3(NPRE + BB), dim3(256), 0, stream,
                     emb, W1, T, edges, dinv, perm, ell, elloff);
  hipLaunchKernelGGL(k_gcn1v, dim3((BB * NN) / 256), dim3(256), 0, stream,
                     ids, cont, T, W1, dinv, yA);
  hipLaunchKernelGGL(k_fused, dim3(BB), dim3(1024), 0, stream,
                     yA, dinv, perm, ell, elloff,
                     b1, W2, b2, W3, b3, W4, b4, Wf1, bf1, Wf2, bf2, out);
}

// Round 21
// 88.377 us; speedup vs baseline: 1.3128x; 1.1306x over previous
//
#include <hip/hip_runtime.h>
#include <hip/hip_bf16.h>

#define BB 512
#define NN 714
#define EE 4096
#define ED2 62
#define CH 32
#define NT16 45    // ceil(NN/16)
#define NPAD 720   // NT16*16
#define VOCAB 38733
#define NPRE 303   // ceil(VOCAB/128) blocks for MFMA emb@W1 precompute
#define ELLR 432   // ELL row capacity (rows of 16 u16), rows per tile padded to x4
#define ELLB (ELLR*16)

typedef unsigned int u32;
typedef unsigned short u16;
typedef short short8 __attribute__((ext_vector_type(8)));
typedef float float4v __attribute__((ext_vector_type(4)));
typedef _Float16 f16x2 __attribute__((ext_vector_type(2)));
typedef __fp16 fp16x2 __attribute__((ext_vector_type(2)));

__device__ __forceinline__ u32 f2bf(float f) {
  u32 u = __float_as_uint(f);
  return (u + 0x7fffu + ((u >> 16) & 1u)) >> 16;
}
__device__ __forceinline__ u32 pack2(float a, float b) {
  return f2bf(a) | (f2bf(b) << 16);
}
__device__ __forceinline__ f16x2 u2h(u32 x) { union { u32 u; f16x2 h; } c; c.u = x; return c.h; }
__device__ __forceinline__ u32 packh(float a, float b) {
  union { fp16x2 h; u32 u; } c;
  c.h = __builtin_amdgcn_cvt_pkrtz(a, b);
  return c.u;
}

// y-in-LDS swizzle: uint4 slot q of node -> q ^ ((node>>1)&3).
__device__ __forceinline__ int yslot(int node, int q) {
  return (node << 2) | (q ^ ((node >> 1) & 3));
}

// ---------------- Fused setup kernel ----------------
// blocks [0, NPRE): T = emb @ [W1_0 | W1_1] via MFMA -> fp16 [VOCAB][64] (32 u32/row)
// blocks [NPRE, NPRE+BB): per-batch degree/dinv/perm/ELL prep
__global__ __launch_bounds__(256) void k_setup(const float* __restrict__ emb,
    const float* __restrict__ W1, u32* __restrict__ Tg,
    const int* __restrict__ edges,
    float* __restrict__ dinv, u16* __restrict__ perm_g,
    u16* __restrict__ ell_g, u16* __restrict__ elloff_g)
{
  const int tid = threadIdx.x;
  if (blockIdx.x < NPRE) {
    const int base = blockIdx.x * 128;
    const int lane = tid & 63, wv = tid >> 6;
    const int col = lane & 15, kg = lane >> 4;
    __shared__ __align__(16) unsigned short sX[128 * 64];   // 16 KB bf16 tile
    for (int s = tid; s < 1024; s += 256) {
      const int row = s >> 3, ck = s & 7;
      uint4 w = {0, 0, 0, 0};
      if (base + row < VOCAB) {
        const float2* __restrict__ p = (const float2*)(emb + (size_t)(base + row) * ED2 + ck * 8);
        float2 v0 = p[0], v1 = p[1], v2 = p[2];
        float2 v3; v3.x = 0.f; v3.y = 0.f;
        if (ck != 7) v3 = p[3];
        w.x = pack2(v0.x, v0.y); w.y = pack2(v1.x, v1.y);
        w.z = pack2(v2.x, v2.y); w.w = pack2(v3.x, v3.y);
      }
      ((uint4*)sX)[(row * 8 + ck) ^ (row & 7)] = w;
    }
    union { u32 u[4]; short8 v; } A[2][4];
#pragma unroll
    for (int kc = 0; kc < 2; ++kc)
#pragma unroll
      for (int hh = 0; hh < 4; ++hh) {
        const int tbl = hh >> 1;
        const int ch = ((hh & 1) * 16) + col;
#pragma unroll
        for (int jj = 0; jj < 4; ++jj) {
          const int k0 = kc * 32 + kg * 8 + 2 * jj;
          const int k1 = k0 + 1;
          const float wa = (k0 < 62) ? W1[(tbl * 62 + k0) * CH + ch] : 0.f;
          const float wb = (k1 < 62) ? W1[(tbl * 62 + k1) * CH + ch] : 0.f;
          A[kc][hh].u[jj] = pack2(wa, wb);
        }
      }
    __syncthreads();
    for (int t = wv; t < 8; t += 4) {
      const int ln = t * 16 + col;
      float4v acc[4];
#pragma unroll
      for (int hh = 0; hh < 4; ++hh) { acc[hh][0] = 0.f; acc[hh][1] = 0.f; acc[hh][2] = 0.f; acc[hh][3] = 0.f; }
#pragma unroll
      for (int kc = 0; kc < 2; ++kc) {
        const int idx8 = (ln * 8 + kc * 4 + kg) ^ (ln & 7);
        short8 bf = *(const short8*)(sX + idx8 * 8);
#pragma unroll
        for (int hh = 0; hh < 4; ++hh)
          acc[hh] = __builtin_amdgcn_mfma_f32_16x16x32_bf16(A[kc][hh].v, bf, acc[hh], 0, 0, 0);
      }
      const int row = base + ln;
      if (row < VOCAB) {
        u32* op = Tg + (size_t)row * 32;
#pragma unroll
        for (int hh = 0; hh < 4; ++hh) {
          uint2 s0 = { packh(acc[hh][0], acc[hh][1]), packh(acc[hh][2], acc[hh][3]) };
          *(uint2*)(op + hh * 8 + 2 * kg) = s0;
        }
      }
    }
    return;
  }
  const int b = blockIdx.x - NPRE;
  const int* __restrict__ er = edges + (size_t)b * 2 * EE;       // e[0] = source (row)
  const int* __restrict__ ec = er + EE;                          // e[1] = target (col)
  __shared__ int s_cnt[NN];
  __shared__ int s_a[1024];
  __shared__ int s_b[1024];
  __shared__ u16 s_rows16[EE];
  __shared__ u16 s_perm[NPAD];
  __shared__ u16 s_degP[NPAD];
  __shared__ int s_hist[64];
  __shared__ int s_md[NT16 + 1];

  for (int i = tid; i < NN; i += 256) s_cnt[i] = 0;
  __syncthreads();
  for (int e = tid; e < EE; e += 256) atomicAdd(&s_cnt[ec[e]], 1);
  __syncthreads();
  for (int i = tid; i < 1024; i += 256) s_a[i] = (i < NN) ? s_cnt[i] : 0;
  for (int i = tid; i < NN; i += 256)
    dinv[(size_t)b * NN + i] = rsqrtf((float)(s_cnt[i] + 1));    // +1 self loop
  __syncthreads();
  int* src = s_a; int* dst = s_b;
  for (int d = 1; d < 1024; d <<= 1) {
    for (int i = tid; i < 1024; i += 256) {
      int v = src[i];
      if (i >= d) v += src[i - d];
      dst[i] = v;
    }
    __syncthreads();
    int* t = src; src = dst; dst = t;
  }
  // src (= s_a, 10 swaps) = inclusive scan of degree counts
  for (int i = tid; i < NN; i += 256) s_cnt[i] = 0;  // fill cursors
  __syncthreads();
  for (int e = tid; e < EE; e += 256) {
    int c = ec[e];
    int p = atomicAdd(&s_cnt[c], 1);
    int base = (c == 0) ? 0 : src[c - 1];
    s_rows16[base + p] = (u16)er[e];
  }
  // degree-sorted perm (counting sort, 64 bins)
  for (int i = tid; i < 64; i += 256) s_hist[i] = 0;
  for (int i = tid; i < NPAD; i += 256) { s_perm[i] = 0xFFFFu; s_degP[i] = 0; }
  __syncthreads();
  for (int i = tid; i < NN; i += 256) {
    int deg = src[i] - (i ? src[i - 1] : 0);
    atomicAdd(&s_hist[deg < 63 ? deg : 63], 1);
  }
  __syncthreads();
  // wave-parallel exclusive scan of the 64 histogram bins
  if (tid < 64) {
    int v = s_hist[tid];
    int incl = v;
#pragma unroll
    for (int d = 1; d < 64; d <<= 1) {
      int o = __shfl_up(incl, d, 64);
      if (tid >= d) incl += o;
    }
    s_hist[tid] = incl - v;
  }
  __syncthreads();
  for (int i = tid; i < NN; i += 256) {
    int deg = src[i] - (i ? src[i - 1] : 0);
    int pos = atomicAdd(&s_hist[deg < 63 ? deg : 63], 1);
    s_perm[pos] = (u16)i;
    s_degP[pos] = (u16)deg;
  }
  __syncthreads();
  for (int i = tid; i < NPAD; i += 256) perm_g[(size_t)b * NPAD + i] = s_perm[i];
  // per-tile max degree, padded to multiple of 4
  if (tid < NT16) {
    int md = 0;
#pragma unroll
    for (int c = 0; c < 16; ++c) { int d = s_degP[tid * 16 + c]; md = d > md ? d : md; }
    s_md[tid] = (md + 3) & ~3;
  }
  __syncthreads();
  // wave-parallel exclusive scan of the 45 tile sizes (clamped to ELLR)
  if (tid < 64) {
    int m = (tid < NT16) ? s_md[tid] : 0;
    int incl = m;
#pragma unroll
    for (int d = 1; d < 64; d <<= 1) {
      int o = __shfl_up(incl, d, 64);
      if (tid >= d) incl += o;
    }
    int excl = incl - m;
    if (excl > ELLR) excl = ELLR;
    if (tid < NT16) s_md[tid] = excl;
    if (tid == NT16 - 1) s_md[NT16] = (incl > ELLR) ? ELLR : incl;
  }
  __syncthreads();
  if (tid <= NT16) elloff_g[(size_t)b * (NT16 + 1) + tid] = (u16)s_md[tid];
  // fill ELL per-wave (wave w takes tiles w, w+4, ...), PRE-SWIZZLED entries (pad -> dummy NN)
  {
    const int wv4 = tid >> 6, lane = tid & 63;
    u16* eg = ell_g + (size_t)b * ELLB;
    for (int t = wv4; t < NT16; t += 4) {
      const int base = s_md[t], md4 = s_md[t + 1] - base;
      for (int s = lane; s < md4 * 16; s += 64) {
        const int kk = s >> 4, col = s & 15;
        const int pv = s_perm[t * 16 + col];
        int r = NN;
        if (pv != 0xFFFF) {
          const int deg = s_degP[t * 16 + col];
          if (kk < deg) {
            const int off = pv ? src[pv - 1] : 0;
            r = (int)s_rows16[off + kk];
          }
        }
        eg[base * 16 + s] = (u16)((r << 2) | ((r >> 1) & 3));
      }
    }
  }
}

// ---------------- Fused kernel: GCN1 table-gather + layers 2,3,4 + tail ----------------
#define EDGEA(EP, K) { const int a16 = ((int)(EP)[(K) * 16]) ^ kg; \
  uint4 n = sy4[a16]; \
  a0h += u2h(n.x); a1h += u2h(n.y); a2h += u2h(n.z); a3h += u2h(n.w); }
#define EDGEB(EP, K) { const int a16 = ((int)(EP)[(K) * 16]) ^ kg; \
  uint4 n = sy4[a16]; \
  b0h += u2h(n.x); b1h += u2h(n.y); b2h += u2h(n.z); b3h += u2h(n.w); }
#define FLUSH { a0h += b0h; a1h += b1h; a2h += b2h; a3h += b3h; \
  zx[0] += (float)a0h.x; zx[1] += (float)a0h.y; \
  zx[2] += (float)a1h.x; zx[3] += (float)a1h.y; \
  zx[4] += (float)a2h.x; zx[5] += (float)a2h.y; \
  zx[6] += (float)a3h.x; zx[7] += (float)a3h.y; \
  a0h = hz; a1h = hz; a2h = hz; a3h = hz; \
  b0h = hz; b1h = hz; b2h = hz; b3h = hz; }
#define AGG_LOOP(EP) { int kk = 0; \
  while (kk + 16 <= md4) { \
    _Pragma("unroll") for (int e = 0; e < 16; e += 2) { EDGEA(EP, kk + e) EDGEB(EP, kk + e + 1) } \
    FLUSH \
    kk += 16; } \
  if (kk + 8 <= md4) { \
    _Pragma("unroll") for (int e = 0; e < 8; e += 2) { EDGEA(EP, kk + e) EDGEB(EP, kk + e + 1) } \
    FLUSH \
    kk += 8; } \
  if (kk < md4) { \
    _Pragma("unroll") for (int e = 0; e < 4; e += 2) { EDGEA(EP, kk + e) EDGEB(EP, kk + e + 1) } \
    FLUSH } }

template<int ACT>
__device__ __forceinline__ void gcn_pass32(
    u32* __restrict__ sy, const u16* __restrict__ s_ell,
    const u16* __restrict__ s_elloff, const float* __restrict__ s_dv,
    const u16* __restrict__ pvs,
    const int wv, const int col, const int kg,
    const short8 a0v, const short8 a1v, const float* __restrict__ bias8)
{
  const uint4* sy4 = (const uint4*)sy;
  const f16x2 hz = {(_Float16)0, (_Float16)0};
  u32 outs[3][4];
  int nodes[3];
#pragma unroll
  for (int p = 0; p < 3; ++p) {
    const int t = p * 16 + wv;
    const int pv = (t < NT16) ? (int)pvs[p] : 0xFFFF;
    const int node = (pv == 0xFFFF) ? NN : pv;
    nodes[p] = (pv == 0xFFFF) ? -1 : pv;
    int base = 0, md4 = 0;
    if (t < NT16) { base = s_elloff[t]; md4 = s_elloff[t + 1] - base; }
    base = __builtin_amdgcn_readfirstlane(base);
    md4 = __builtin_amdgcn_readfirstlane(md4);
    f16x2 a0h, a1h, a2h, a3h;
    f16x2 b0h = hz, b1h = hz, b2h = hz, b3h = hz;
    {
      uint4 u = sy4[yslot(node, kg)];          // self (dummy row = zeros)
      a0h = u2h(u.x); a1h = u2h(u.y); a2h = u2h(u.z); a3h = u2h(u.w);
    }
    float zx[8];
#pragma unroll
    for (int j = 0; j < 8; ++j) zx[j] = 0.f;
    const u16* ep = s_ell + base * 16 + col;
    AGG_LOOP(ep)
    const float dv = s_dv[node];               // dummy dv = 0
    float h[8];
#pragma unroll
    for (int j = 0; j < 8; ++j) {
      float t2 = fmaf(dv, zx[j], bias8[j]);
      float l = (t2 > 0.f) ? t2 : 0.01f * t2;
      h[j] = (ACT == 0) ? l : (l + t2);
    }
    union { u32 u[4]; short8 v; } ub;
#pragma unroll
    for (int jj = 0; jj < 4; ++jj) ub.u[jj] = pack2(h[2 * jj], h[2 * jj + 1]);
    float4v z4 = {0.f, 0.f, 0.f, 0.f};
    float4v d0 = __builtin_amdgcn_mfma_f32_16x16x32_bf16(a0v, ub.v, z4, 0, 0, 0);
    float4v d1 = __builtin_amdgcn_mfma_f32_16x16x32_bf16(a1v, ub.v, z4, 0, 0, 0);
    outs[p][0] = packh(d0[0] * dv, d0[1] * dv);
    outs[p][1] = packh(d0[2] * dv, d0[3] * dv);
    outs[p][2] = packh(d1[0] * dv, d1[1] * dv);
    outs[p][3] = packh(d1[2] * dv, d1[3] * dv);
  }
  __syncthreads();
#pragma unroll
  for (int p = 0; p < 3; ++p) {
    const int node = nodes[p];
    if (node >= 0) {
      const int sw = (node >> 1) & 3;
      u32* op = sy + node * 16;
      uint2 s0 = { outs[p][0], outs[p][1] };
      uint2 s1 = { outs[p][2], outs[p][3] };
      *(uint2*)(op + (((kg >> 1) ^ sw) << 2) + ((2 * kg) & 3)) = s0;
      *(uint2*)(op + (((2 + (kg >> 1)) ^ sw) << 2) + ((2 * kg) & 3)) = s1;
    }
  }
  __syncthreads();
}

__global__ __launch_bounds__(1024) void k_fused(
    const int* __restrict__ ids, const float* __restrict__ cont,
    const u32* __restrict__ T, const float* __restrict__ W1,
    const float* __restrict__ dinv,
    const u16* __restrict__ perm_g, const u16* __restrict__ ell_g,
    const u16* __restrict__ elloff_g,
    const float* __restrict__ b1, const float* __restrict__ W2,
    const float* __restrict__ b2, const float* __restrict__ W3,
    const float* __restrict__ b3, const float* __restrict__ W4,
    const float* __restrict__ b4, const float* __restrict__ Wf1,
    const float* __restrict__ bf1, const float* __restrict__ Wf2,
    const float* __restrict__ bf2, float* __restrict__ out)
{
  const int b = blockIdx.x;
  const int tid = threadIdx.x;
  const int lane = tid & 63;
  const int wv = tid >> 6;          // wave 0..15
  const int col = lane & 15;
  const int kg = lane >> 4;

  __shared__ __align__(16) char smem[65408];
  u32*   s_y      = (u32*)smem;                     // 45760 B (715 rows; dead later)
  u16*   s_ell    = (u16*)(smem + 45760);           // 13824
  u16*   s_elloff = (u16*)(smem + 59584);           // 96
  float* s_dv     = (float*)(smem + 59680);         // 2864 (incl dummy)
  float* s_h      = (float*)(smem + 62544);         // 2864 (sWc during staging; layer-4 out later)
  float* s_red    = (float*)smem;                   // aliases dead s_y
  float* s_u      = (float*)(smem + 8192);          // aliases dead s_y

  // phase A: ELL/meta staging + cont-weight cache + dummy y row
  {
    const uint4 z4 = {0, 0, 0, 0};
    uint4* sy4w = (uint4*)s_y;
    if (tid < 4) sy4w[yslot(NN, tid)] = z4;
    const uint4* __restrict__ esrc = (const uint4*)(ell_g + (size_t)b * ELLB);
    uint4* ed = (uint4*)s_ell;
    for (int s = tid; s < ELLB / 8; s += 1024) ed[s] = esrc[s];
    for (int i = tid; i <= NT16; i += 1024) s_elloff[i] = elloff_g[(size_t)b * (NT16 + 1) + i];
    for (int i = tid; i < NN; i += 1024) s_dv[i] = dinv[(size_t)b * NN + i];
    if (tid == 1023) s_dv[NN] = 0.f;
    if (tid < 96) s_h[tid] = W1[124 * 32 + tid];
  }
  __syncthreads();
  // phase B: GCN1 via table gather, write y straight into s_y (swizzled)
  if (tid < NN) {
    const int node = tid;
    const int2 id2 = ((const int2*)ids)[(size_t)b * NN + node];
    const uint4* __restrict__ t0 = (const uint4*)(T + (size_t)id2.x * 32);        // ch 0..31
    const uint4* __restrict__ t1 = (const uint4*)(T + (size_t)id2.y * 32 + 16);   // ch 32..63
    uint4 q0 = t0[0], q1 = t0[1], q2 = t0[2], q3 = t0[3];
    uint4 r0 = t1[0], r1 = t1[1], r2 = t1[2], r3 = t1[3];
    const float* __restrict__ c3 = cont + ((size_t)b * NN + node) * 3;
    const float c0 = c3[0], c1 = c3[1], c2 = c3[2];
    const float dv = s_dv[node];
    const u32 qs[16] = { q0.x, q0.y, q0.z, q0.w, q1.x, q1.y, q1.z, q1.w,
                         q2.x, q2.y, q2.z, q2.w, q3.x, q3.y, q3.z, q3.w };
    const u32 rs[16] = { r0.x, r0.y, r0.z, r0.w, r1.x, r1.y, r1.z, r1.w,
                         r2.x, r2.y, r2.z, r2.w, r3.x, r3.y, r3.z, r3.w };
    u32 os[16];
#pragma unroll
    for (int s = 0; s < 16; ++s) {
      f16x2 a = u2h(qs[s]);
      f16x2 bb = u2h(rs[s]);
      const int ch = 2 * s;
      float v0 = (float)a.x + (float)bb.x;
      float v1 = (float)a.y + (float)bb.y;
      v0 = fmaf(c0, s_h[ch],      v0);
      v1 = fmaf(c0, s_h[ch + 1],  v1);
      v0 = fmaf(c1, s_h[32 + ch],     v0);
      v1 = fmaf(c1, s_h[32 + ch + 1], v1);
      v0 = fmaf(c2, s_h[64 + ch],     v0);
      v1 = fmaf(c2, s_h[64 + ch + 1], v1);
      os[s] = packh(v0 * dv, v1 * dv);
    }
    uint4* sy4w = (uint4*)s_y;
#pragma unroll
    for (int s4 = 0; s4 < 4; ++s4) {
      uint4 w = { os[4 * s4], os[4 * s4 + 1], os[4 * s4 + 2], os[4 * s4 + 3] };
      sy4w[yslot(node, s4)] = w;
    }
  }
  u16 pvs[3];
#pragma unroll
  for (int p = 0; p < 3; ++p) {
    const int t = p * 16 + wv;
    pvs[p] = (t < NT16) ? perm_g[(size_t)b * NPAD + t * 16 + col] : (u16)0xFFFF;
  }
  const u16 pvt = (tid < NPAD) ? perm_g[(size_t)b * NPAD + tid] : (u16)0xFFFF;

  union { u32 u[4]; short8 v; } uaA0, uaA1, uaB0, uaB1;
#pragma unroll
  for (int jj = 0; jj < 4; ++jj) {
    uaA0.u[jj] = pack2(W2[(kg * 8 + 2 * jj) * CH + col],      W2[(kg * 8 + 2 * jj + 1) * CH + col]);
    uaA1.u[jj] = pack2(W2[(kg * 8 + 2 * jj) * CH + 16 + col], W2[(kg * 8 + 2 * jj + 1) * CH + 16 + col]);
    uaB0.u[jj] = pack2(W3[(kg * 8 + 2 * jj) * CH + col],      W3[(kg * 8 + 2 * jj + 1) * CH + col]);
    uaB1.u[jj] = pack2(W3[(kg * 8 + 2 * jj) * CH + 16 + col], W3[(kg * 8 + 2 * jj + 1) * CH + 16 + col]);
  }
  float b1r[8], b2r[8], b3r[8], w4r[8];
#pragma unroll
  for (int j = 0; j < 8; ++j) {
    b1r[j] = b1[kg * 8 + j];
    b2r[j] = b2[kg * 8 + j];
    b3r[j] = b3[kg * 8 + j];
    w4r[j] = W4[kg * 8 + j];
  }
  const float bb4 = b4[0];
  __syncthreads();

  gcn_pass32<0>(s_y, s_ell, s_elloff, s_dv, pvs, wv, col, kg, uaA0.v, uaA1.v, b1r);
  gcn_pass32<1>(s_y, s_ell, s_elloff, s_dv, pvs, wv, col, kg, uaB0.v, uaB1.v, b2r);

  // layer 4: agg + b3, lrelu+t, dot W4 (32->1), *dinv -> s_h
  {
    const uint4* sy4 = (const uint4*)s_y;
    const f16x2 hz = {(_Float16)0, (_Float16)0};
#pragma unroll
    for (int p = 0; p < 3; ++p) {
      const int t = p * 16 + wv;
      const int pv = (t < NT16) ? (int)pvs[p] : 0xFFFF;
      const int node = (pv == 0xFFFF) ? NN : pv;
      int base = 0, md4 = 0;
      if (t < NT16) { base = s_elloff[t]; md4 = s_elloff[t + 1] - base; }
      base = __builtin_amdgcn_readfirstlane(base);
      md4 = __builtin_amdgcn_readfirstlane(md4);
      f16x2 a0h, a1h, a2h, a3h;
      f16x2 b0h = hz, b1h = hz, b2h = hz, b3h = hz;
      {
        uint4 u = sy4[yslot(node, kg)];
        a0h = u2h(u.x); a1h = u2h(u.y); a2h = u2h(u.z); a3h = u2h(u.w);
      }
      float zx[8];
#pragma unroll
      for (int j = 0; j < 8; ++j) zx[j] = 0.f;
      const u16* ep = s_ell + base * 16 + col;
      AGG_LOOP(ep)
      const float dv = s_dv[node];
      float part = 0.f;
#pragma unroll
      for (int j = 0; j < 8; ++j) {
        float t2 = fmaf(dv, zx[j], b3r[j]);
        float l = (t2 > 0.f) ? t2 : 0.01f * t2;
        part = fmaf(l + t2, w4r[j], part);
      }
      part += __shfl_xor(part, 16, 64);
      part += __shfl_xor(part, 32, 64);
      if (pv != 0xFFFF && kg == 0) s_h[node] = part * dv;
    }
  }
  __syncthreads();
  if (tid == 1023) s_h[NN] = 0.f;
  __syncthreads();

  // tail aggregation via ELL: z = h[node] + sum h[e0>>2]; lrelu(dinv*z + b4)
  {
    float hval = 0.f;
    int node = -1;
    if (tid < NPAD && pvt != 0xFFFF) {
      node = (int)pvt;
      const int t = tid >> 4, c = tid & 15;
      const int base = s_elloff[t], md4 = s_elloff[t + 1] - base;
      float z = s_h[node];
      const u16* ep = s_ell + base * 16 + c;
      for (int kk = 0; kk < md4; ++kk) z += s_h[((int)ep[kk * 16]) >> 2];
      float t2 = fmaf(s_dv[node], z, bb4);
      hval = (t2 > 0.f) ? t2 : 0.01f * t2;
    }
    __syncthreads();
    if (node >= 0) s_h[node] = hval;
  }
  __syncthreads();

  // FC1: 714 -> 128, 8-way split-K
  const int j = tid & 127, q = tid >> 7;
  {
    const int n0 = (q * NN) >> 3, n1 = ((q + 1) * NN) >> 3;
    const float* __restrict__ w = Wf1 + j;
    float a0 = 0.f, a1 = 0.f;
    int n = n0;
#pragma unroll 4
    for (; n + 2 <= n1; n += 2) {
      a0 = fmaf(s_h[n], w[(size_t)n * 128], a0);
      a1 = fmaf(s_h[n + 1], w[(size_t)(n + 1) * 128], a1);
    }
    if (n < n1) a0 = fmaf(s_h[n], w[(size_t)n * 128], a0);
    s_red[tid] = a0 + a1;
  }
  __syncthreads();
  if (tid < 128) {
    float v = bf1[tid];
#pragma unroll
    for (int m = 0; m < 8; ++m) v += s_red[tid + 128 * m];
    s_u[tid] = fmaxf(v, 0.f);
  }
  __syncthreads();
  // FC2: 128 -> 128, 8-way split-K
  {
    const float* __restrict__ w = Wf2 + j;
    float a0 = 0.f, a1 = 0.f;
#pragma unroll
    for (int k = q * 16; k < q * 16 + 16; k += 2) {
      a0 = fmaf(s_u[k], w[(size_t)k * 128], a0);
      a1 = fmaf(s_u[k + 1], w[(size_t)(k + 1) * 128], a1);
    }
    s_red[tid] = a0 + a1;
  }
  __syncthreads();
  if (tid < 128) {
    float v = bf2[tid];
#pragma unroll
    for (int m = 0; m < 8; ++m) v += s_red[tid + 128 * m];
    out[(size_t)b * 128 + tid] = fmaxf(v, 0.f);
  }
}

extern "C" void kernel_launch(void* const* d_in, const int* in_sizes, int n_in,
                              void* d_out, int out_size, void* d_ws, size_t ws_size,
                              hipStream_t stream)
{
  (void)in_sizes; (void)n_in; (void)out_size; (void)ws_size;
  const int*   ids  = (const int*)d_in[0];
  const float* cont = (const float*)d_in[1];
  const int*   edges= (const int*)d_in[2];
  const float* emb  = (const float*)d_in[3];
  const float* W1   = (const float*)d_in[4];
  const float* b1   = (const float*)d_in[5];
  const float* W2   = (const float*)d_in[6];
  const float* b2   = (const float*)d_in[7];
  const float* W3   = (const float*)d_in[8];
  const float* b3   = (const float*)d_in[9];
  const float* W4   = (const float*)d_in[10];
  const float* b4   = (const float*)d_in[11];
  const float* Wf1  = (const float*)d_in[12];
  const float* bf1  = (const float*)d_in[13];
  const float* Wf2  = (const float*)d_in[14];
  const float* bf2  = (const float*)d_in[15];
  float* out = (float*)d_out;

  char* ws = (char*)d_ws;
  size_t off = 0;
  auto alloc = [&](size_t bytes) -> void* {
    void* p = ws + off;
    off = (off + bytes + 255) & ~(size_t)255;
    return p;
  };
  float* dinv     = (float*)alloc((size_t)BB * NN * 4);
  u16*   perm     = (u16*)  alloc((size_t)BB * NPAD * 2);
  u16*   ell      = (u16*)  alloc((size_t)BB * ELLB * 2);
  u16*   elloff   = (u16*)  alloc((size_t)BB * (NT16 + 1) * 2);
  u32*   T        = (u32*)  alloc((size_t)VOCAB * 32 * 4);   // fp16 [VOCAB][64]

  hipLaunchKernelGGL(k_setup, dim3(NPRE + BB), dim3(256), 0, stream,
                     emb, W1, T, edges, dinv, perm, ell, elloff);
  hipLaunchKernelGGL(k_fused, dim3(BB), dim3(1024), 0, stream,
                     ids, cont, T, W1, dinv, perm, ell, elloff,
                     b1, W2, b2, W3, b3, W4, b4, Wf1, bf1, Wf2, bf2, out);
}

// Round 22
// 83.181 us; speedup vs baseline: 1.3948x; 1.0625x over previous
//
#include <hip/hip_runtime.h>
#include <hip/hip_bf16.h>

#define BB 512
#define NN 714
#define EE 4096
#define ED2 62
#define CH 32
#define NT16 45    // ceil(NN/16)
#define NPAD 720   // NT16*16
#define VOCAB 38733
#define NPRE 303   // ceil(VOCAB/128) blocks for MFMA emb@W1 precompute
#define ELLR 432   // ELL row capacity (rows of 16 u16), rows per tile padded to x4
#define ELLB (ELLR*16)
#define DYN_LDS 66848

typedef unsigned int u32;
typedef unsigned short u16;
typedef short short8 __attribute__((ext_vector_type(8)));
typedef float float4v __attribute__((ext_vector_type(4)));
typedef _Float16 f16x2 __attribute__((ext_vector_type(2)));
typedef __fp16 fp16x2 __attribute__((ext_vector_type(2)));

__device__ __forceinline__ u32 f2bf(float f) {
  u32 u = __float_as_uint(f);
  return (u + 0x7fffu + ((u >> 16) & 1u)) >> 16;
}
__device__ __forceinline__ u32 pack2(float a, float b) {
  return f2bf(a) | (f2bf(b) << 16);
}
__device__ __forceinline__ f16x2 u2h(u32 x) { union { u32 u; f16x2 h; } c; c.u = x; return c.h; }
__device__ __forceinline__ u32 packh(float a, float b) {
  union { fp16x2 h; u32 u; } c;
  c.h = __builtin_amdgcn_cvt_pkrtz(a, b);
  return c.u;
}

// y-in-LDS swizzle: uint4 slot q of node -> q ^ ((node>>1)&3).
__device__ __forceinline__ int yslot(int node, int q) {
  return (node << 2) | (q ^ ((node >> 1) & 3));
}

// ---------------- Kernel A: T = emb @ [W1_0 | W1_1] via MFMA -> fp16 [VOCAB][64] ----------------
__global__ __launch_bounds__(256) void k_setup(const float* __restrict__ emb,
    const float* __restrict__ W1, u32* __restrict__ Tg)
{
  const int tid = threadIdx.x;
  const int base = blockIdx.x * 128;
  const int lane = tid & 63, wv = tid >> 6;
  const int col = lane & 15, kg = lane >> 4;
  __shared__ __align__(16) unsigned short sX[128 * 64];   // 16 KB bf16 tile
  for (int s = tid; s < 1024; s += 256) {
    const int row = s >> 3, ck = s & 7;
    uint4 w = {0, 0, 0, 0};
    if (base + row < VOCAB) {
      const float2* __restrict__ p = (const float2*)(emb + (size_t)(base + row) * ED2 + ck * 8);
      float2 v0 = p[0], v1 = p[1], v2 = p[2];
      float2 v3; v3.x = 0.f; v3.y = 0.f;
      if (ck != 7) v3 = p[3];
      w.x = pack2(v0.x, v0.y); w.y = pack2(v1.x, v1.y);
      w.z = pack2(v2.x, v2.y); w.w = pack2(v3.x, v3.y);
    }
    ((uint4*)sX)[(row * 8 + ck) ^ (row & 7)] = w;
  }
  union { u32 u[4]; short8 v; } A[2][4];
#pragma unroll
  for (int kc = 0; kc < 2; ++kc)
#pragma unroll
    for (int hh = 0; hh < 4; ++hh) {
      const int tbl = hh >> 1;
      const int ch = ((hh & 1) * 16) + col;
#pragma unroll
      for (int jj = 0; jj < 4; ++jj) {
        const int k0 = kc * 32 + kg * 8 + 2 * jj;
        const int k1 = k0 + 1;
        const float wa = (k0 < 62) ? W1[(tbl * 62 + k0) * CH + ch] : 0.f;
        const float wb = (k1 < 62) ? W1[(tbl * 62 + k1) * CH + ch] : 0.f;
        A[kc][hh].u[jj] = pack2(wa, wb);
      }
    }
  __syncthreads();
  for (int t = wv; t < 8; t += 4) {
    const int ln = t * 16 + col;
    float4v acc[4];
#pragma unroll
    for (int hh = 0; hh < 4; ++hh) { acc[hh][0] = 0.f; acc[hh][1] = 0.f; acc[hh][2] = 0.f; acc[hh][3] = 0.f; }
#pragma unroll
    for (int kc = 0; kc < 2; ++kc) {
      const int idx8 = (ln * 8 + kc * 4 + kg) ^ (ln & 7);
      short8 bf = *(const short8*)(sX + idx8 * 8);
#pragma unroll
      for (int hh = 0; hh < 4; ++hh)
        acc[hh] = __builtin_amdgcn_mfma_f32_16x16x32_bf16(A[kc][hh].v, bf, acc[hh], 0, 0, 0);
    }
    const int row = base + ln;
    if (row < VOCAB) {
      u32* op = Tg + (size_t)row * 32;
#pragma unroll
      for (int hh = 0; hh < 4; ++hh) {
        uint2 s0 = { packh(acc[hh][0], acc[hh][1]), packh(acc[hh][2], acc[hh][3]) };
        *(uint2*)(op + hh * 8 + 2 * kg) = s0;
      }
    }
  }
}

// ---------------- Fused kernel: prep + GCN1 gather + layers 2,3,4 + tail ----------------
#define EDGEA(EP, K) { const int a16 = ((int)(EP)[(K) * 16]) ^ kg; \
  uint4 n = sy4[a16]; \
  a0h += u2h(n.x); a1h += u2h(n.y); a2h += u2h(n.z); a3h += u2h(n.w); }
#define EDGEB(EP, K) { const int a16 = ((int)(EP)[(K) * 16]) ^ kg; \
  uint4 n = sy4[a16]; \
  b0h += u2h(n.x); b1h += u2h(n.y); b2h += u2h(n.z); b3h += u2h(n.w); }
#define FLUSH { a0h += b0h; a1h += b1h; a2h += b2h; a3h += b3h; \
  zx[0] += (float)a0h.x; zx[1] += (float)a0h.y; \
  zx[2] += (float)a1h.x; zx[3] += (float)a1h.y; \
  zx[4] += (float)a2h.x; zx[5] += (float)a2h.y; \
  zx[6] += (float)a3h.x; zx[7] += (float)a3h.y; \
  a0h = hz; a1h = hz; a2h = hz; a3h = hz; \
  b0h = hz; b1h = hz; b2h = hz; b3h = hz; }
#define AGG_LOOP(EP) { int kk = 0; \
  while (kk + 16 <= md4) { \
    _Pragma("unroll") for (int e = 0; e < 16; e += 2) { EDGEA(EP, kk + e) EDGEB(EP, kk + e + 1) } \
    FLUSH \
    kk += 16; } \
  if (kk + 8 <= md4) { \
    _Pragma("unroll") for (int e = 0; e < 8; e += 2) { EDGEA(EP, kk + e) EDGEB(EP, kk + e + 1) } \
    FLUSH \
    kk += 8; } \
  if (kk < md4) { \
    _Pragma("unroll") for (int e = 0; e < 4; e += 2) { EDGEA(EP, kk + e) EDGEB(EP, kk + e + 1) } \
    FLUSH } }

template<int ACT>
__device__ __forceinline__ void gcn_pass32(
    u32* __restrict__ sy, const u16* __restrict__ s_ell,
    const u16* __restrict__ s_elloff, const float* __restrict__ s_dv,
    const u16* __restrict__ pvs,
    const int wv, const int col, const int kg,
    const short8 a0v, const short8 a1v, const float* __restrict__ bias8)
{
  const uint4* sy4 = (const uint4*)sy;
  const f16x2 hz = {(_Float16)0, (_Float16)0};
  u32 outs[3][4];
  int nodes[3];
#pragma unroll
  for (int p = 0; p < 3; ++p) {
    const int t = p * 16 + wv;
    const int pv = (t < NT16) ? (int)pvs[p] : 0xFFFF;
    const int node = (pv == 0xFFFF) ? NN : pv;
    nodes[p] = (pv == 0xFFFF) ? -1 : pv;
    int base = 0, md4 = 0;
    if (t < NT16) { base = s_elloff[t]; md4 = s_elloff[t + 1] - base; }
    base = __builtin_amdgcn_readfirstlane(base);
    md4 = __builtin_amdgcn_readfirstlane(md4);
    f16x2 a0h, a1h, a2h, a3h;
    f16x2 b0h = hz, b1h = hz, b2h = hz, b3h = hz;
    {
      uint4 u = sy4[yslot(node, kg)];          // self (dummy row = zeros)
      a0h = u2h(u.x); a1h = u2h(u.y); a2h = u2h(u.z); a3h = u2h(u.w);
    }
    float zx[8];
#pragma unroll
    for (int j = 0; j < 8; ++j) zx[j] = 0.f;
    const u16* ep = s_ell + base * 16 + col;
    AGG_LOOP(ep)
    const float dv = s_dv[node];               // dummy dv = 0
    float h[8];
#pragma unroll
    for (int j = 0; j < 8; ++j) {
      float t2 = fmaf(dv, zx[j], bias8[j]);
      float l = (t2 > 0.f) ? t2 : 0.01f * t2;
      h[j] = (ACT == 0) ? l : (l + t2);
    }
    union { u32 u[4]; short8 v; } ub;
#pragma unroll
    for (int jj = 0; jj < 4; ++jj) ub.u[jj] = pack2(h[2 * jj], h[2 * jj + 1]);
    float4v z4 = {0.f, 0.f, 0.f, 0.f};
    float4v d0 = __builtin_amdgcn_mfma_f32_16x16x32_bf16(a0v, ub.v, z4, 0, 0, 0);
    float4v d1 = __builtin_amdgcn_mfma_f32_16x16x32_bf16(a1v, ub.v, z4, 0, 0, 0);
    outs[p][0] = packh(d0[0] * dv, d0[1] * dv);
    outs[p][1] = packh(d0[2] * dv, d0[3] * dv);
    outs[p][2] = packh(d1[0] * dv, d1[1] * dv);
    outs[p][3] = packh(d1[2] * dv, d1[3] * dv);
  }
  __syncthreads();
#pragma unroll
  for (int p = 0; p < 3; ++p) {
    const int node = nodes[p];
    if (node >= 0) {
      const int sw = (node >> 1) & 3;
      u32* op = sy + node * 16;
      uint2 s0 = { outs[p][0], outs[p][1] };
      uint2 s1 = { outs[p][2], outs[p][3] };
      *(uint2*)(op + (((kg >> 1) ^ sw) << 2) + ((2 * kg) & 3)) = s0;
      *(uint2*)(op + (((2 + (kg >> 1)) ^ sw) << 2) + ((2 * kg) & 3)) = s1;
    }
  }
  __syncthreads();
}

__global__ __launch_bounds__(1024) void k_fused(
    const int* __restrict__ ids, const float* __restrict__ cont,
    const int* __restrict__ edges,
    const u32* __restrict__ T, const float* __restrict__ W1,
    const float* __restrict__ b1, const float* __restrict__ W2,
    const float* __restrict__ b2, const float* __restrict__ W3,
    const float* __restrict__ b3, const float* __restrict__ W4,
    const float* __restrict__ b4, const float* __restrict__ Wf1,
    const float* __restrict__ bf1, const float* __restrict__ Wf2,
    const float* __restrict__ bf2, float* __restrict__ out)
{
  const int b = blockIdx.x;
  const int tid = threadIdx.x;
  const int lane = tid & 63;
  const int wv = tid >> 6;          // wave 0..15
  const int col = lane & 15;
  const int kg = lane >> 4;

  extern __shared__ __align__(16) char smem[];
  // persistent regions
  u32*   s_y      = (u32*)smem;                     // 45760 B (715 rows; overlay home)
  u16*   s_ell    = (u16*)(smem + 45760);           // 13824
  u16*   s_elloff = (u16*)(smem + 59584);           // 96
  float* s_dv     = (float*)(smem + 59680);         // 2864 (incl dummy)
  float* s_h      = (float*)(smem + 62544);         // 2864 (Wc during staging; layer-4 out later)
  u16*   s_perm   = (u16*)(smem + 65408);           // 1440
  float* s_red    = (float*)smem;                   // aliases dead s_y (FC)
  float* s_u      = (float*)(smem + 8192);          // aliases dead s_y (FC)
  // phase-0 overlay inside s_y region
  int*   s_cnt    = (int*)smem;                     // 2856
  int*   s_csr    = (int*)(smem + 2944);            // 2856 (inclusive degree scan)
  u16*   s_rows16 = (u16*)(smem + 5888);            // 8192
  u16*   s_degP   = (u16*)(smem + 14080);           // 1440
  int*   s_md     = (int*)(smem + 15520);           // 256 (64 ints; hist then tile offsets)
  int*   s_wsum   = (int*)(smem + 15776);           // 64

  // ---------------- phase 0: per-batch prep entirely in LDS ----------------
  const int* __restrict__ er = edges + (size_t)b * 2 * EE;   // source (row)
  const int* __restrict__ ec = er + EE;                      // target (col)
  for (int i = tid; i < NN; i += 1024) s_cnt[i] = 0;
  if (tid < 96) s_h[tid] = W1[124 * 32 + tid];               // Wc cache
  __syncthreads();
  for (int e = tid; e < EE; e += 1024) atomicAdd(&s_cnt[ec[e]], 1);
  __syncthreads();
  const int deg = (tid < NN) ? s_cnt[tid] : 0;
  if (tid < NN) s_dv[tid] = rsqrtf((float)(deg + 1));
  if (tid == 0) s_dv[NN] = 0.f;
  // inclusive scan of degrees over 1024 slots (1 elem/thread)
  {
    int incl = deg;
#pragma unroll
    for (int d = 1; d < 64; d <<= 1) {
      int o = __shfl_up(incl, d, 64);
      if (lane >= d) incl += o;
    }
    if (lane == 63) s_wsum[wv] = incl;
    __syncthreads();
    if (wv == 0 && lane < 16) {
      int v = s_wsum[lane];
      int ic = v;
#pragma unroll
      for (int d = 1; d < 16; d <<= 1) {
        int o = __shfl_up(ic, d, 16);
        if (lane >= d) ic += o;
      }
      s_wsum[lane] = ic - v;   // exclusive wave offset
    }
    __syncthreads();
    incl += s_wsum[wv];
    if (tid < NN) s_csr[tid] = incl;
  }
  __syncthreads();
  for (int i = tid; i < NN; i += 1024) s_cnt[i] = 0;  // fill cursors
  __syncthreads();
  for (int e = tid; e < EE; e += 1024) {
    const int c = ec[e];
    const int p = atomicAdd(&s_cnt[c], 1);
    const int off = c ? s_csr[c - 1] : 0;
    s_rows16[off + p] = (u16)er[e];
  }
  // degree-sorted perm (counting sort, 64 bins)
  if (tid < 64) s_md[tid] = 0;
  for (int i = tid; i < NPAD; i += 1024) { s_perm[i] = 0xFFFFu; s_degP[i] = 0; }
  __syncthreads();
  if (tid < NN) atomicAdd(&s_md[deg < 63 ? deg : 63], 1);
  __syncthreads();
  if (tid < 64) {
    int v = s_md[tid];
    int incl = v;
#pragma unroll
    for (int d = 1; d < 64; d <<= 1) {
      int o = __shfl_up(incl, d, 64);
      if (tid >= d) incl += o;
    }
    s_md[tid] = incl - v;
  }
  __syncthreads();
  if (tid < NN) {
    const int pos = atomicAdd(&s_md[deg < 63 ? deg : 63], 1);
    s_perm[pos] = (u16)tid;
    s_degP[pos] = (u16)deg;
  }
  __syncthreads();
  // per-tile max degree (pad4) + clamped exclusive scan
  if (tid < NT16) {
    int md = 0;
#pragma unroll
    for (int c = 0; c < 16; ++c) { int d = s_degP[tid * 16 + c]; md = d > md ? d : md; }
    s_md[tid] = (md + 3) & ~3;
  }
  __syncthreads();
  if (tid < 64) {
    int m = (tid < NT16) ? s_md[tid] : 0;
    int incl = m;
#pragma unroll
    for (int d = 1; d < 64; d <<= 1) {
      int o = __shfl_up(incl, d, 64);
      if (tid >= d) incl += o;
    }
    int excl = incl - m;
    if (excl > ELLR) excl = ELLR;
    if (tid < NT16) s_md[tid] = excl;
    if (tid == NT16 - 1) s_md[NT16] = (incl > ELLR) ? ELLR : incl;
  }
  __syncthreads();
  if (tid <= NT16) s_elloff[tid] = (u16)s_md[tid];
  // ELL fill straight into LDS (16 waves; pre-swizzled entries; pad -> dummy NN)
  for (int t = wv; t < NT16; t += 16) {
    const int base = s_md[t], md4 = s_md[t + 1] - base;
    for (int s = lane; s < md4 * 16; s += 64) {
      const int kk = s >> 4, c = s & 15;
      const int pv = s_perm[t * 16 + c];
      int r = NN;
      if (pv != 0xFFFF) {
        const int dg = s_degP[t * 16 + c];
        if (kk < dg) {
          const int off = pv ? s_csr[pv - 1] : 0;
          r = (int)s_rows16[off + kk];
        }
      }
      s_ell[base * 16 + s] = (u16)((r << 2) | ((r >> 1) & 3));
    }
  }
  __syncthreads();   // prep done; overlay region (s_cnt..s_wsum) is now dead

  // ---------------- phase B: GCN1 via table gather, write y into s_y (swizzled) ----------------
  {
    uint4* sy4w = (uint4*)s_y;
    if (tid < 4) { const uint4 z4 = {0, 0, 0, 0}; sy4w[yslot(NN, tid)] = z4; }
    if (tid < NN) {
      const int node = tid;
      const int2 id2 = ((const int2*)ids)[(size_t)b * NN + node];
      const uint4* __restrict__ t0 = (const uint4*)(T + (size_t)id2.x * 32);        // ch 0..31
      const uint4* __restrict__ t1 = (const uint4*)(T + (size_t)id2.y * 32 + 16);   // ch 32..63
      uint4 q0 = t0[0], q1 = t0[1], q2 = t0[2], q3 = t0[3];
      uint4 r0 = t1[0], r1 = t1[1], r2 = t1[2], r3 = t1[3];
      const float* __restrict__ c3 = cont + ((size_t)b * NN + node) * 3;
      const float c0 = c3[0], c1 = c3[1], c2 = c3[2];
      const float dv = s_dv[node];
      const u32 qs[16] = { q0.x, q0.y, q0.z, q0.w, q1.x, q1.y, q1.z, q1.w,
                           q2.x, q2.y, q2.z, q2.w, q3.x, q3.y, q3.z, q3.w };
      const u32 rs[16] = { r0.x, r0.y, r0.z, r0.w, r1.x, r1.y, r1.z, r1.w,
                           r2.x, r2.y, r2.z, r2.w, r3.x, r3.y, r3.z, r3.w };
      u32 os[16];
#pragma unroll
      for (int s = 0; s < 16; ++s) {
        f16x2 a = u2h(qs[s]);
        f16x2 bb = u2h(rs[s]);
        const int ch = 2 * s;
        float v0 = (float)a.x + (float)bb.x;
        float v1 = (float)a.y + (float)bb.y;
        v0 = fmaf(c0, s_h[ch],      v0);
        v1 = fmaf(c0, s_h[ch + 1],  v1);
        v0 = fmaf(c1, s_h[32 + ch],     v0);
        v1 = fmaf(c1, s_h[32 + ch + 1], v1);
        v0 = fmaf(c2, s_h[64 + ch],     v0);
        v1 = fmaf(c2, s_h[64 + ch + 1], v1);
        os[s] = packh(v0 * dv, v1 * dv);
      }
#pragma unroll
      for (int s4 = 0; s4 < 4; ++s4) {
        uint4 w = { os[4 * s4], os[4 * s4 + 1], os[4 * s4 + 2], os[4 * s4 + 3] };
        sy4w[yslot(node, s4)] = w;
      }
    }
  }
  u16 pvs[3];
#pragma unroll
  for (int p = 0; p < 3; ++p) {
    const int t = p * 16 + wv;
    pvs[p] = (t < NT16) ? s_perm[t * 16 + col] : (u16)0xFFFF;
  }
  const u16 pvt = (tid < NPAD) ? s_perm[tid] : (u16)0xFFFF;

  union { u32 u[4]; short8 v; } uaA0, uaA1, uaB0, uaB1;
#pragma unroll
  for (int jj = 0; jj < 4; ++jj) {
    uaA0.u[jj] = pack2(W2[(kg * 8 + 2 * jj) * CH + col],      W2[(kg * 8 + 2 * jj + 1) * CH + col]);
    uaA1.u[jj] = pack2(W2[(kg * 8 + 2 * jj) * CH + 16 + col], W2[(kg * 8 + 2 * jj + 1) * CH + 16 + col]);
    uaB0.u[jj] = pack2(W3[(kg * 8 + 2 * jj) * CH + col],      W3[(kg * 8 + 2 * jj + 1) * CH + col]);
    uaB1.u[jj] = pack2(W3[(kg * 8 + 2 * jj) * CH + 16 + col], W3[(kg * 8 + 2 * jj + 1) * CH + 16 + col]);
  }
  float b1r[8], b2r[8], b3r[8], w4r[8];
#pragma unroll
  for (int j = 0; j < 8; ++j) {
    b1r[j] = b1[kg * 8 + j];
    b2r[j] = b2[kg * 8 + j];
    b3r[j] = b3[kg * 8 + j];
    w4r[j] = W4[kg * 8 + j];
  }
  const float bb4 = b4[0];
  __syncthreads();

  gcn_pass32<0>(s_y, s_ell, s_elloff, s_dv, pvs, wv, col, kg, uaA0.v, uaA1.v, b1r);
  gcn_pass32<1>(s_y, s_ell, s_elloff, s_dv, pvs, wv, col, kg, uaB0.v, uaB1.v, b2r);

  // layer 4: agg + b3, lrelu+t, dot W4 (32->1), *dinv -> s_h
  {
    const uint4* sy4 = (const uint4*)s_y;
    const f16x2 hz = {(_Float16)0, (_Float16)0};
#pragma unroll
    for (int p = 0; p < 3; ++p) {
      const int t = p * 16 + wv;
      const int pv = (t < NT16) ? (int)pvs[p] : 0xFFFF;
      const int node = (pv == 0xFFFF) ? NN : pv;
      int base = 0, md4 = 0;
      if (t < NT16) { base = s_elloff[t]; md4 = s_elloff[t + 1] - base; }
      base = __builtin_amdgcn_readfirstlane(base);
      md4 = __builtin_amdgcn_readfirstlane(md4);
      f16x2 a0h, a1h, a2h, a3h;
      f16x2 b0h = hz, b1h = hz, b2h = hz, b3h = hz;
      {
        uint4 u = sy4[yslot(node, kg)];
        a0h = u2h(u.x); a1h = u2h(u.y); a2h = u2h(u.z); a3h = u2h(u.w);
      }
      float zx[8];
#pragma unroll
      for (int j = 0; j < 8; ++j) zx[j] = 0.f;
      const u16* ep = s_ell + base * 16 + col;
      AGG_LOOP(ep)
      const float dv = s_dv[node];
      float part = 0.f;
#pragma unroll
      for (int j = 0; j < 8; ++j) {
        float t2 = fmaf(dv, zx[j], b3r[j]);
        float l = (t2 > 0.f) ? t2 : 0.01f * t2;
        part = fmaf(l + t2, w4r[j], part);
      }
      part += __shfl_xor(part, 16, 64);
      part += __shfl_xor(part, 32, 64);
      if (pv != 0xFFFF && kg == 0) s_h[node] = part * dv;
    }
  }
  __syncthreads();
  if (tid == 1023) s_h[NN] = 0.f;
  __syncthreads();

  // tail aggregation via ELL: z = h[node] + sum h[e0>>2]; lrelu(dinv*z + b4)
  {
    float hval = 0.f;
    int node = -1;
    if (tid < NPAD && pvt != 0xFFFF) {
      node = (int)pvt;
      const int t = tid >> 4, c = tid & 15;
      const int base = s_elloff[t], md4 = s_elloff[t + 1] - base;
      float z = s_h[node];
      const u16* ep = s_ell + base * 16 + c;
      for (int kk = 0; kk < md4; ++kk) z += s_h[((int)ep[kk * 16]) >> 2];
      float t2 = fmaf(s_dv[node], z, bb4);
      hval = (t2 > 0.f) ? t2 : 0.01f * t2;
    }
    __syncthreads();
    if (node >= 0) s_h[node] = hval;
  }
  __syncthreads();

  // FC1: 714 -> 128, 8-way split-K
  const int j = tid & 127, q = tid >> 7;
  {
    const int n0 = (q * NN) >> 3, n1 = ((q + 1) * NN) >> 3;
    const float* __restrict__ w = Wf1 + j;
    float a0 = 0.f, a1 = 0.f;
    int n = n0;
#pragma unroll 4
    for (; n + 2 <= n1; n += 2) {
      a0 = fmaf(s_h[n], w[(size_t)n * 128], a0);
      a1 = fmaf(s_h[n + 1], w[(size_t)(n + 1) * 128], a1);
    }
    if (n < n1) a0 = fmaf(s_h[n], w[(size_t)n * 128], a0);
    s_red[tid] = a0 + a1;
  }
  __syncthreads();
  if (tid < 128) {
    float v = bf1[tid];
#pragma unroll
    for (int m = 0; m < 8; ++m) v += s_red[tid + 128 * m];
    s_u[tid] = fmaxf(v, 0.f);
  }
  __syncthreads();
  // FC2: 128 -> 128, 8-way split-K
  {
    const float* __restrict__ w = Wf2 + j;
    float a0 = 0.f, a1 = 0.f;
#pragma unroll
    for (int k = q * 16; k < q * 16 + 16; k += 2) {
      a0 = fmaf(s_u[k], w[(size_t)k * 128], a0);
      a1 = fmaf(s_u[k + 1], w[(size_t)(k + 1) * 128], a1);
    }
    s_red[tid] = a0 + a1;
  }
  __syncthreads();
  if (tid < 128) {
    float v = bf2[tid];
#pragma unroll
    for (int m = 0; m < 8; ++m) v += s_red[tid + 128 * m];
    out[(size_t)b * 128 + tid] = fmaxf(v, 0.f);
  }
}

extern "C" void kernel_launch(void* const* d_in, const int* in_sizes, int n_in,
                              void* d_out, int out_size, void* d_ws, size_t ws_size,
                              hipStream_t stream)
{
  (void)in_sizes; (void)n_in; (void)out_size; (void)ws_size;
  const int*   ids  = (const int*)d_in[0];
  const float* cont = (const float*)d_in[1];
  const int*   edges= (const int*)d_in[2];
  const float* emb  = (const float*)d_in[3];
  const float* W1   = (const float*)d_in[4];
  const float* b1   = (const float*)d_in[5];
  const float* W2   = (const float*)d_in[6];
  const float* b2   = (const float*)d_in[7];
  const float* W3   = (const float*)d_in[8];
  const float* b3   = (const float*)d_in[9];
  const float* W4   = (const float*)d_in[10];
  const float* b4   = (const float*)d_in[11];
  const float* Wf1  = (const float*)d_in[12];
  const float* bf1  = (const float*)d_in[13];
  const float* Wf2  = (const float*)d_in[14];
  const float* bf2  = (const float*)d_in[15];
  float* out = (float*)d_out;

  char* ws = (char*)d_ws;
  size_t off = 0;
  auto alloc = [&](size_t bytes) -> void* {
    void* p = ws + off;
    off = (off + bytes + 255) & ~(size_t)255;
    return p;
  };
  u32* T = (u32*)alloc((size_t)VOCAB * 32 * 4);   // fp16 [VOCAB][64]

  hipLaunchKernelGGL(k_setup, dim3(NPRE), dim3(256), 0, stream, emb, W1, T);
  hipLaunchKernelGGL(k_fused, dim3(BB), dim3(1024), DYN_LDS, stream,
                     ids, cont, edges, T, W1,
                     b1, W2, b2, W3, b3, W4, b4, Wf1, bf1, Wf2, bf2, out);
}

// Round 23
// 76.593 us; speedup vs baseline: 1.5148x; 1.0860x over previous
//
#include <hip/hip_runtime.h>
#include <hip/hip_bf16.h>

#define BB 512
#define NN 714
#define EE 4096
#define ED2 62
#define CH 32
#define NT16 45    // ceil(NN/16)
#define NPAD 720   // NT16*16
#define VOCAB 38733
#define NPRE 303   // ceil(VOCAB/128) blocks for MFMA emb@W1 precompute
#define ELLR 432   // ELL row capacity (rows of 16 u16), rows per tile padded to x4
#define ELLB (ELLR*16)
#define DYN_LDS 66848

typedef unsigned int u32;
typedef unsigned short u16;
typedef short short8 __attribute__((ext_vector_type(8)));
typedef float float4v __attribute__((ext_vector_type(4)));
typedef _Float16 f16x2 __attribute__((ext_vector_type(2)));
typedef __fp16 fp16x2 __attribute__((ext_vector_type(2)));

__device__ __forceinline__ u32 f2bf(float f) {
  u32 u = __float_as_uint(f);
  return (u + 0x7fffu + ((u >> 16) & 1u)) >> 16;
}
__device__ __forceinline__ u32 pack2(float a, float b) {
  return f2bf(a) | (f2bf(b) << 16);
}
__device__ __forceinline__ f16x2 u2h(u32 x) { union { u32 u; f16x2 h; } c; c.u = x; return c.h; }
__device__ __forceinline__ u32 packh(float a, float b) {
  union { fp16x2 h; u32 u; } c;
  c.h = __builtin_amdgcn_cvt_pkrtz(a, b);
  return c.u;
}

// y-in-LDS swizzle: uint4 slot q of node -> q ^ ((node>>1)&3).
__device__ __forceinline__ int yslot(int node, int q) {
  return (node << 2) | (q ^ ((node >> 1) & 3));
}

// ---------------- Kernel A: T = emb @ [W1_0 | W1_1] via MFMA -> fp16 [VOCAB][64] ----------------
__global__ __launch_bounds__(256) void k_setup(const float* __restrict__ emb,
    const float* __restrict__ W1, u32* __restrict__ Tg)
{
  const int tid = threadIdx.x;
  const int base = blockIdx.x * 128;
  const int lane = tid & 63, wv = tid >> 6;
  const int col = lane & 15, kg = lane >> 4;
  __shared__ __align__(16) unsigned short sX[128 * 64];   // 16 KB bf16 tile
  for (int s = tid; s < 1024; s += 256) {
    const int row = s >> 3, ck = s & 7;
    uint4 w = {0, 0, 0, 0};
    if (base + row < VOCAB) {
      const float2* __restrict__ p = (const float2*)(emb + (size_t)(base + row) * ED2 + ck * 8);
      float2 v0 = p[0], v1 = p[1], v2 = p[2];
      float2 v3; v3.x = 0.f; v3.y = 0.f;
      if (ck != 7) v3 = p[3];
      w.x = pack2(v0.x, v0.y); w.y = pack2(v1.x, v1.y);
      w.z = pack2(v2.x, v2.y); w.w = pack2(v3.x, v3.y);
    }
    ((uint4*)sX)[(row * 8 + ck) ^ (row & 7)] = w;
  }
  union { u32 u[4]; short8 v; } A[2][4];
#pragma unroll
  for (int kc = 0; kc < 2; ++kc)
#pragma unroll
    for (int hh = 0; hh < 4; ++hh) {
      const int tbl = hh >> 1;
      const int ch = ((hh & 1) * 16) + col;
#pragma unroll
      for (int jj = 0; jj < 4; ++jj) {
        const int k0 = kc * 32 + kg * 8 + 2 * jj;
        const int k1 = k0 + 1;
        const float wa = (k0 < 62) ? W1[(tbl * 62 + k0) * CH + ch] : 0.f;
        const float wb = (k1 < 62) ? W1[(tbl * 62 + k1) * CH + ch] : 0.f;
        A[kc][hh].u[jj] = pack2(wa, wb);
      }
    }
  __syncthreads();
  for (int t = wv; t < 8; t += 4) {
    const int ln = t * 16 + col;
    float4v acc[4];
#pragma unroll
    for (int hh = 0; hh < 4; ++hh) { acc[hh][0] = 0.f; acc[hh][1] = 0.f; acc[hh][2] = 0.f; acc[hh][3] = 0.f; }
#pragma unroll
    for (int kc = 0; kc < 2; ++kc) {
      const int idx8 = (ln * 8 + kc * 4 + kg) ^ (ln & 7);
      short8 bf = *(const short8*)(sX + idx8 * 8);
#pragma unroll
      for (int hh = 0; hh < 4; ++hh)
        acc[hh] = __builtin_amdgcn_mfma_f32_16x16x32_bf16(A[kc][hh].v, bf, acc[hh], 0, 0, 0);
    }
    const int row = base + ln;
    if (row < VOCAB) {
      u32* op = Tg + (size_t)row * 32;
#pragma unroll
      for (int hh = 0; hh < 4; ++hh) {
        uint2 s0 = { packh(acc[hh][0], acc[hh][1]), packh(acc[hh][2], acc[hh][3]) };
        *(uint2*)(op + hh * 8 + 2 * kg) = s0;
      }
    }
  }
}

// ---------------- Fused kernel: prep + GCN1 gather + layers 2,3,4 + tail ----------------
#define EDGEA(EP, K) { const int a16 = ((int)(EP)[(K) * 16]) ^ kg; \
  uint4 n = sy4[a16]; \
  a0h += u2h(n.x); a1h += u2h(n.y); a2h += u2h(n.z); a3h += u2h(n.w); }
#define EDGEB(EP, K) { const int a16 = ((int)(EP)[(K) * 16]) ^ kg; \
  uint4 n = sy4[a16]; \
  b0h += u2h(n.x); b1h += u2h(n.y); b2h += u2h(n.z); b3h += u2h(n.w); }
#define FLUSH { a0h += b0h; a1h += b1h; a2h += b2h; a3h += b3h; \
  zx[0] += (float)a0h.x; zx[1] += (float)a0h.y; \
  zx[2] += (float)a1h.x; zx[3] += (float)a1h.y; \
  zx[4] += (float)a2h.x; zx[5] += (float)a2h.y; \
  zx[6] += (float)a3h.x; zx[7] += (float)a3h.y; \
  a0h = hz; a1h = hz; a2h = hz; a3h = hz; \
  b0h = hz; b1h = hz; b2h = hz; b3h = hz; }
#define AGG_LOOP(EP) { int kk = 0; \
  while (kk + 16 <= md4) { \
    _Pragma("unroll") for (int e = 0; e < 16; e += 2) { EDGEA(EP, kk + e) EDGEB(EP, kk + e + 1) } \
    FLUSH \
    kk += 16; } \
  if (kk + 8 <= md4) { \
    _Pragma("unroll") for (int e = 0; e < 8; e += 2) { EDGEA(EP, kk + e) EDGEB(EP, kk + e + 1) } \
    FLUSH \
    kk += 8; } \
  if (kk < md4) { \
    _Pragma("unroll") for (int e = 0; e < 4; e += 2) { EDGEA(EP, kk + e) EDGEB(EP, kk + e + 1) } \
    FLUSH } }

template<int ACT>
__device__ __forceinline__ void gcn_pass32(
    u32* __restrict__ sy, const u16* __restrict__ s_ell,
    const u16* __restrict__ s_elloff, const float* __restrict__ s_dv,
    const u16* __restrict__ pvs,
    const int wv, const int col, const int kg,
    const short8 a0v, const short8 a1v, const float* __restrict__ bias8)
{
  const uint4* sy4 = (const uint4*)sy;
  const f16x2 hz = {(_Float16)0, (_Float16)0};
  u32 outs[3][4];
  int nodes[3];
#pragma unroll
  for (int p = 0; p < 3; ++p) {
    const int t = p * 16 + wv;
    const int pv = (t < NT16) ? (int)pvs[p] : 0xFFFF;
    const int node = (pv == 0xFFFF) ? NN : pv;
    nodes[p] = (pv == 0xFFFF) ? -1 : pv;
    int base = 0, md4 = 0;
    if (t < NT16) { base = s_elloff[t]; md4 = s_elloff[t + 1] - base; }
    base = __builtin_amdgcn_readfirstlane(base);
    md4 = __builtin_amdgcn_readfirstlane(md4);
    f16x2 a0h, a1h, a2h, a3h;
    f16x2 b0h = hz, b1h = hz, b2h = hz, b3h = hz;
    {
      uint4 u = sy4[yslot(node, kg)];          // self (dummy row = zeros)
      a0h = u2h(u.x); a1h = u2h(u.y); a2h = u2h(u.z); a3h = u2h(u.w);
    }
    float zx[8];
#pragma unroll
    for (int j = 0; j < 8; ++j) zx[j] = 0.f;
    const u16* ep = s_ell + base * 16 + col;
    AGG_LOOP(ep)
    const float dv = s_dv[node];               // dummy dv = 0
    float h[8];
#pragma unroll
    for (int j = 0; j < 8; ++j) {
      float t2 = fmaf(dv, zx[j], bias8[j]);
      float l = (t2 > 0.f) ? t2 : 0.01f * t2;
      h[j] = (ACT == 0) ? l : (l + t2);
    }
    union { u32 u[4]; short8 v; } ub;
#pragma unroll
    for (int jj = 0; jj < 4; ++jj) ub.u[jj] = pack2(h[2 * jj], h[2 * jj + 1]);
    float4v z4 = {0.f, 0.f, 0.f, 0.f};
    float4v d0 = __builtin_amdgcn_mfma_f32_16x16x32_bf16(a0v, ub.v, z4, 0, 0, 0);
    float4v d1 = __builtin_amdgcn_mfma_f32_16x16x32_bf16(a1v, ub.v, z4, 0, 0, 0);
    outs[p][0] = packh(d0[0] * dv, d0[1] * dv);
    outs[p][1] = packh(d0[2] * dv, d0[3] * dv);
    outs[p][2] = packh(d1[0] * dv, d1[1] * dv);
    outs[p][3] = packh(d1[2] * dv, d1[3] * dv);
  }
  __syncthreads();
#pragma unroll
  for (int p = 0; p < 3; ++p) {
    const int node = nodes[p];
    if (node >= 0) {
      const int sw = (node >> 1) & 3;
      u32* op = sy + node * 16;
      uint2 s0 = { outs[p][0], outs[p][1] };
      uint2 s1 = { outs[p][2], outs[p][3] };
      *(uint2*)(op + (((kg >> 1) ^ sw) << 2) + ((2 * kg) & 3)) = s0;
      *(uint2*)(op + (((2 + (kg >> 1)) ^ sw) << 2) + ((2 * kg) & 3)) = s1;
    }
  }
  __syncthreads();
}

__global__ __launch_bounds__(1024) void k_fused(
    const int* __restrict__ ids, const float* __restrict__ cont,
    const int* __restrict__ edges,
    const u32* __restrict__ T, const float* __restrict__ W1,
    const float* __restrict__ b1, const float* __restrict__ W2,
    const float* __restrict__ b2, const float* __restrict__ W3,
    const float* __restrict__ b3, const float* __restrict__ W4,
    const float* __restrict__ b4, const float* __restrict__ Wf1,
    const float* __restrict__ bf1, const float* __restrict__ Wf2,
    const float* __restrict__ bf2, float* __restrict__ out)
{
  const int b = blockIdx.x;
  const int tid = threadIdx.x;
  const int lane = tid & 63;
  const int wv = tid >> 6;          // wave 0..15
  const int col = lane & 15;
  const int kg = lane >> 4;

  extern __shared__ __align__(16) char smem[];
  // persistent regions
  u32*   s_y      = (u32*)smem;                     // 45760 B (715 rows; overlay home)
  u16*   s_ell    = (u16*)(smem + 45760);           // 13824
  u16*   s_elloff = (u16*)(smem + 59584);           // 96
  float* s_dv     = (float*)(smem + 59680);         // 2864 (incl dummy)
  float* s_h      = (float*)(smem + 62544);         // 2864 (Wc during staging; layer-4 out later)
  u16*   s_perm   = (u16*)(smem + 65408);           // 1440
  float* s_red    = (float*)smem;                   // aliases dead s_y (FC)
  float* s_u      = (float*)(smem + 8192);          // aliases dead s_y (FC)
  // phase-0 overlay inside s_y region
  int*   s_cnt    = (int*)smem;                     // 2856
  int*   s_csr    = (int*)(smem + 2944);            // 2856 (inclusive degree scan)
  u16*   s_rows16 = (u16*)(smem + 5888);            // 8192
  u16*   s_degP   = (u16*)(smem + 14080);           // 1440
  int*   s_md     = (int*)(smem + 15520);           // 256 (64 ints; hist then tile offsets)
  int*   s_wsum   = (int*)(smem + 15776);           // 64

  // ---------------- phase 0: per-batch prep entirely in LDS ----------------
  const int* __restrict__ er = edges + (size_t)b * 2 * EE;   // source (row)
  const int* __restrict__ ec = er + EE;                      // target (col)
  for (int i = tid; i < NN; i += 1024) s_cnt[i] = 0;
  if (tid < 96) s_h[tid] = W1[124 * 32 + tid];               // Wc cache
  __syncthreads();
  {
    const int4 ec4 = ((const int4*)ec)[tid];                 // 1024 x 4 = 4096 exactly
    atomicAdd(&s_cnt[ec4.x], 1);
    atomicAdd(&s_cnt[ec4.y], 1);
    atomicAdd(&s_cnt[ec4.z], 1);
    atomicAdd(&s_cnt[ec4.w], 1);
  }
  __syncthreads();
  const int deg = (tid < NN) ? s_cnt[tid] : 0;
  if (tid < NN) s_dv[tid] = rsqrtf((float)(deg + 1));
  if (tid == 0) s_dv[NN] = 0.f;
  // inclusive scan of degrees over 1024 slots (1 elem/thread)
  {
    int incl = deg;
#pragma unroll
    for (int d = 1; d < 64; d <<= 1) {
      int o = __shfl_up(incl, d, 64);
      if (lane >= d) incl += o;
    }
    if (lane == 63) s_wsum[wv] = incl;
    __syncthreads();
    if (wv == 0 && lane < 16) {
      int v = s_wsum[lane];
      int ic = v;
#pragma unroll
      for (int d = 1; d < 16; d <<= 1) {
        int o = __shfl_up(ic, d, 16);
        if (lane >= d) ic += o;
      }
      s_wsum[lane] = ic - v;   // exclusive wave offset
    }
    __syncthreads();
    incl += s_wsum[wv];
    if (tid < NN) s_csr[tid] = incl;
  }
  __syncthreads();
  for (int i = tid; i < NN; i += 1024) s_cnt[i] = 0;  // fill cursors
  __syncthreads();
  {
    const int4 ec4 = ((const int4*)ec)[tid];
    const int4 er4 = ((const int4*)er)[tid];
    {
      const int c = ec4.x; const int p = atomicAdd(&s_cnt[c], 1);
      s_rows16[(c ? s_csr[c - 1] : 0) + p] = (u16)er4.x;
    }
    {
      const int c = ec4.y; const int p = atomicAdd(&s_cnt[c], 1);
      s_rows16[(c ? s_csr[c - 1] : 0) + p] = (u16)er4.y;
    }
    {
      const int c = ec4.z; const int p = atomicAdd(&s_cnt[c], 1);
      s_rows16[(c ? s_csr[c - 1] : 0) + p] = (u16)er4.z;
    }
    {
      const int c = ec4.w; const int p = atomicAdd(&s_cnt[c], 1);
      s_rows16[(c ? s_csr[c - 1] : 0) + p] = (u16)er4.w;
    }
  }
  // degree-sorted perm (counting sort, 64 bins)
  if (tid < 64) s_md[tid] = 0;
  for (int i = tid; i < NPAD; i += 1024) { s_perm[i] = 0xFFFFu; s_degP[i] = 0; }
  __syncthreads();
  if (tid < NN) atomicAdd(&s_md[deg < 63 ? deg : 63], 1);
  __syncthreads();
  if (tid < 64) {
    int v = s_md[tid];
    int incl = v;
#pragma unroll
    for (int d = 1; d < 64; d <<= 1) {
      int o = __shfl_up(incl, d, 64);
      if (tid >= d) incl += o;
    }
    s_md[tid] = incl - v;
  }
  __syncthreads();
  if (tid < NN) {
    const int pos = atomicAdd(&s_md[deg < 63 ? deg : 63], 1);
    s_perm[pos] = (u16)tid;
    s_degP[pos] = (u16)deg;
  }
  __syncthreads();
  // per-tile max degree (pad4) + clamped exclusive scan
  if (tid < NT16) {
    int md = 0;
#pragma unroll
    for (int c = 0; c < 16; ++c) { int d = s_degP[tid * 16 + c]; md = d > md ? d : md; }
    s_md[tid] = (md + 3) & ~3;
  }
  __syncthreads();
  if (tid < 64) {
    int m = (tid < NT16) ? s_md[tid] : 0;
    int incl = m;
#pragma unroll
    for (int d = 1; d < 64; d <<= 1) {
      int o = __shfl_up(incl, d, 64);
      if (tid >= d) incl += o;
    }
    int excl = incl - m;
    if (excl > ELLR) excl = ELLR;
    if (tid < NT16) s_md[tid] = excl;
    if (tid == NT16 - 1) s_md[NT16] = (incl > ELLR) ? ELLR : incl;
  }
  __syncthreads();
  if (tid <= NT16) s_elloff[tid] = (u16)s_md[tid];
  // ELL fill straight into LDS (16 waves; pre-swizzled entries; pad -> dummy NN)
  for (int t = wv; t < NT16; t += 16) {
    const int base = s_md[t], md4 = s_md[t + 1] - base;
    for (int s = lane; s < md4 * 16; s += 64) {
      const int kk = s >> 4, c = s & 15;
      const int pv = s_perm[t * 16 + c];
      int r = NN;
      if (pv != 0xFFFF) {
        const int dg = s_degP[t * 16 + c];
        if (kk < dg) {
          const int off = pv ? s_csr[pv - 1] : 0;
          r = (int)s_rows16[off + kk];
        }
      }
      s_ell[base * 16 + s] = (u16)((r << 2) | ((r >> 1) & 3));
    }
  }
  __syncthreads();   // prep done; overlay region (s_cnt..s_wsum) is now dead

  // ---------------- phase B: GCN1 via table gather, (node, half) items ----------------
  {
    uint4* sy4w = (uint4*)s_y;
    if (tid < 4) { const uint4 z4 = {0, 0, 0, 0}; sy4w[yslot(NN, tid)] = z4; }
#pragma unroll 1
    for (int item = tid; item < 2 * NN; item += 1024) {
      const int node = item >> 1, half = item & 1;
      const int2 id2 = ((const int2*)ids)[(size_t)b * NN + node];
      const uint4* __restrict__ t0 = (const uint4*)(T + (size_t)id2.x * 32);        // ch 0..31
      const uint4* __restrict__ t1 = (const uint4*)(T + (size_t)id2.y * 32 + 16);   // ch 32..63
      uint4 qa = t0[2 * half], qb = t0[2 * half + 1];
      uint4 ra = t1[2 * half], rb = t1[2 * half + 1];
      const float* __restrict__ c3 = cont + ((size_t)b * NN + node) * 3;
      const float c0 = c3[0], c1 = c3[1], c2 = c3[2];
      const float dv = s_dv[node];
      const u32 qs[8] = { qa.x, qa.y, qa.z, qa.w, qb.x, qb.y, qb.z, qb.w };
      const u32 rs[8] = { ra.x, ra.y, ra.z, ra.w, rb.x, rb.y, rb.z, rb.w };
      u32 os[8];
#pragma unroll
      for (int s = 0; s < 8; ++s) {
        f16x2 a = u2h(qs[s]);
        f16x2 bb = u2h(rs[s]);
        const int ch = 16 * half + 2 * s;
        float v0 = (float)a.x + (float)bb.x;
        float v1 = (float)a.y + (float)bb.y;
        v0 = fmaf(c0, s_h[ch],      v0);
        v1 = fmaf(c0, s_h[ch + 1],  v1);
        v0 = fmaf(c1, s_h[32 + ch],     v0);
        v1 = fmaf(c1, s_h[32 + ch + 1], v1);
        v0 = fmaf(c2, s_h[64 + ch],     v0);
        v1 = fmaf(c2, s_h[64 + ch + 1], v1);
        os[s] = packh(v0 * dv, v1 * dv);
      }
      uint4 w0 = { os[0], os[1], os[2], os[3] };
      uint4 w1 = { os[4], os[5], os[6], os[7] };
      sy4w[yslot(node, 2 * half)] = w0;
      sy4w[yslot(node, 2 * half + 1)] = w1;
    }
  }
  u16 pvs[3];
#pragma unroll
  for (int p = 0; p < 3; ++p) {
    const int t = p * 16 + wv;
    pvs[p] = (t < NT16) ? s_perm[t * 16 + col] : (u16)0xFFFF;
  }
  const u16 pvt = (tid < NPAD) ? s_perm[tid] : (u16)0xFFFF;

  union { u32 u[4]; short8 v; } uaA0, uaA1, uaB0, uaB1;
#pragma unroll
  for (int jj = 0; jj < 4; ++jj) {
    uaA0.u[jj] = pack2(W2[(kg * 8 + 2 * jj) * CH + col],      W2[(kg * 8 + 2 * jj + 1) * CH + col]);
    uaA1.u[jj] = pack2(W2[(kg * 8 + 2 * jj) * CH + 16 + col], W2[(kg * 8 + 2 * jj + 1) * CH + 16 + col]);
    uaB0.u[jj] = pack2(W3[(kg * 8 + 2 * jj) * CH + col],      W3[(kg * 8 + 2 * jj + 1) * CH + col]);
    uaB1.u[jj] = pack2(W3[(kg * 8 + 2 * jj) * CH + 16 + col], W3[(kg * 8 + 2 * jj + 1) * CH + 16 + col]);
  }
  float b1r[8], b2r[8], b3r[8], w4r[8];
#pragma unroll
  for (int j = 0; j < 8; ++j) {
    b1r[j] = b1[kg * 8 + j];
    b2r[j] = b2[kg * 8 + j];
    b3r[j] = b3[kg * 8 + j];
    w4r[j] = W4[kg * 8 + j];
  }
  const float bb4 = b4[0];
  __syncthreads();

  gcn_pass32<0>(s_y, s_ell, s_elloff, s_dv, pvs, wv, col, kg, uaA0.v, uaA1.v, b1r);
  gcn_pass32<1>(s_y, s_ell, s_elloff, s_dv, pvs, wv, col, kg, uaB0.v, uaB1.v, b2r);

  // layer 4: agg + b3, lrelu+t, dot W4 (32->1), *dinv -> s_h
  {
    const uint4* sy4 = (const uint4*)s_y;
    const f16x2 hz = {(_Float16)0, (_Float16)0};
#pragma unroll
    for (int p = 0; p < 3; ++p) {
      const int t = p * 16 + wv;
      const int pv = (t < NT16) ? (int)pvs[p] : 0xFFFF;
      const int node = (pv == 0xFFFF) ? NN : pv;
      int base = 0, md4 = 0;
      if (t < NT16) { base = s_elloff[t]; md4 = s_elloff[t + 1] - base; }
      base = __builtin_amdgcn_readfirstlane(base);
      md4 = __builtin_amdgcn_readfirstlane(md4);
      f16x2 a0h, a1h, a2h, a3h;
      f16x2 b0h = hz, b1h = hz, b2h = hz, b3h = hz;
      {
        uint4 u = sy4[yslot(node, kg)];
        a0h = u2h(u.x); a1h = u2h(u.y); a2h = u2h(u.z); a3h = u2h(u.w);
      }
      float zx[8];
#pragma unroll
      for (int j = 0; j < 8; ++j) zx[j] = 0.f;
      const u16* ep = s_ell + base * 16 + col;
      AGG_LOOP(ep)
      const float dv = s_dv[node];
      float part = 0.f;
#pragma unroll
      for (int j = 0; j < 8; ++j) {
        float t2 = fmaf(dv, zx[j], b3r[j]);
        float l = (t2 > 0.f) ? t2 : 0.01f * t2;
        part = fmaf(l + t2, w4r[j], part);
      }
      part += __shfl_xor(part, 16, 64);
      part += __shfl_xor(part, 32, 64);
      if (pv != 0xFFFF && kg == 0) s_h[node] = part * dv;
    }
  }
  __syncthreads();
  if (tid == 1023) s_h[NN] = 0.f;
  __syncthreads();

  // tail aggregation via ELL: z = h[node] + sum h[e0>>2]; lrelu(dinv*z + b4)
  {
    float hval = 0.f;
    int node = -1;
    if (tid < NPAD && pvt != 0xFFFF) {
      node = (int)pvt;
      const int t = tid >> 4, c = tid & 15;
      const int base = s_elloff[t], md4 = s_elloff[t + 1] - base;
      float z = s_h[node];
      const u16* ep = s_ell + base * 16 + c;
      for (int kk = 0; kk < md4; ++kk) z += s_h[((int)ep[kk * 16]) >> 2];
      float t2 = fmaf(s_dv[node], z, bb4);
      hval = (t2 > 0.f) ? t2 : 0.01f * t2;
    }
    __syncthreads();
    if (node >= 0) s_h[node] = hval;
  }
  __syncthreads();

  // FC1: 714 -> 128, 8-way split-K
  const int j = tid & 127, q = tid >> 7;
  {
    const int n0 = (q * NN) >> 3, n1 = ((q + 1) * NN) >> 3;
    const float* __restrict__ w = Wf1 + j;
    float a0 = 0.f, a1 = 0.f;
    int n = n0;
#pragma unroll 4
    for (; n + 2 <= n1; n += 2) {
      a0 = fmaf(s_h[n], w[(size_t)n * 128], a0);
      a1 = fmaf(s_h[n + 1], w[(size_t)(n + 1) * 128], a1);
    }
    if (n < n1) a0 = fmaf(s_h[n], w[(size_t)n * 128], a0);
    s_red[tid] = a0 + a1;
  }
  __syncthreads();
  if (tid < 128) {
    float v = bf1[tid];
#pragma unroll
    for (int m = 0; m < 8; ++m) v += s_red[tid + 128 * m];
    s_u[tid] = fmaxf(v, 0.f);
  }
  __syncthreads();
  // FC2: 128 -> 128, 8-way split-K
  {
    const float* __restrict__ w = Wf2 + j;
    float a0 = 0.f, a1 = 0.f;
#pragma unroll
    for (int k = q * 16; k < q * 16 + 16; k += 2) {
      a0 = fmaf(s_u[k], w[(size_t)k * 128], a0);
      a1 = fmaf(s_u[k + 1], w[(size_t)(k + 1) * 128], a1);
    }
    s_red[tid] = a0 + a1;
  }
  __syncthreads();
  if (tid < 128) {
    float v = bf2[tid];
#pragma unroll
    for (int m = 0; m < 8; ++m) v += s_red[tid + 128 * m];
    out[(size_t)b * 128 + tid] = fmaxf(v, 0.f);
  }
}

extern "C" void kernel_launch(void* const* d_in, const int* in_sizes, int n_in,
                              void* d_out, int out_size, void* d_ws, size_t ws_size,
                              hipStream_t stream)
{
  (void)in_sizes; (void)n_in; (void)out_size; (void)ws_size;
  const int*   ids  = (const int*)d_in[0];
  const float* cont = (const float*)d_in[1];
  const int*   edges= (const int*)d_in[2];
  const float* emb  = (const float*)d_in[3];
  const float* W1   = (const float*)d_in[4];
  const float* b1   = (const float*)d_in[5];
  const float* W2   = (const float*)d_in[6];
  const float* b2   = (const float*)d_in[7];
  const float* W3   = (const float*)d_in[8];
  const float* b3   = (const float*)d_in[9];
  const float* W4   = (const float*)d_in[10];
  const float* b4   = (const float*)d_in[11];
  const float* Wf1  = (const float*)d_in[12];
  const float* bf1  = (const float*)d_in[13];
  const float* Wf2  = (const float*)d_in[14];
  const float* bf2  = (const float*)d_in[15];
  float* out = (float*)d_out;

  char* ws = (char*)d_ws;
  size_t off = 0;
  auto alloc = [&](size_t bytes) -> void* {
    void* p = ws + off;
    off = (off + bytes + 255) & ~(size_t)255;
    return p;
  };
  u32* T = (u32*)alloc((size_t)VOCAB * 32 * 4);   // fp16 [VOCAB][64]

  hipLaunchKernelGGL(k_setup, dim3(NPRE), dim3(256), 0, stream, emb, W1, T);
  hipLaunchKernelGGL(k_fused, dim3(BB), dim3(1024), DYN_LDS, stream,
                     ids, cont, edges, T, W1,
                     b1, W2, b2, W3, b3, W4, b4, Wf1, bf1, Wf2, bf2, out);
}

// Round 24
// 75.645 us; speedup vs baseline: 1.5338x; 1.0125x over previous
//
#include <hip/hip_runtime.h>
#include <hip/hip_bf16.h>

#define BB 512
#define NN 714
#define EE 4096
#define ED2 62
#define CH 32
#define NT16 45    // ceil(NN/16)
#define NPAD 720   // NT16*16
#define VOCAB 38733
#define NPRE 303   // ceil(VOCAB/128) blocks for MFMA emb@W1 precompute
#define ELLR 432   // ELL row capacity (rows of 16 u16), rows per tile padded to x2
#define ELLB (ELLR*16)
#define DYN_LDS 66848

typedef unsigned int u32;
typedef unsigned short u16;
typedef short short8 __attribute__((ext_vector_type(8)));
typedef float float4v __attribute__((ext_vector_type(4)));
typedef _Float16 f16x2 __attribute__((ext_vector_type(2)));
typedef __fp16 fp16x2 __attribute__((ext_vector_type(2)));

__device__ __forceinline__ u32 f2bf(float f) {
  u32 u = __float_as_uint(f);
  return (u + 0x7fffu + ((u >> 16) & 1u)) >> 16;
}
__device__ __forceinline__ u32 pack2(float a, float b) {
  return f2bf(a) | (f2bf(b) << 16);
}
__device__ __forceinline__ f16x2 u2h(u32 x) { union { u32 u; f16x2 h; } c; c.u = x; return c.h; }
__device__ __forceinline__ u32 packh(float a, float b) {
  union { fp16x2 h; u32 u; } c;
  c.h = __builtin_amdgcn_cvt_pkrtz(a, b);
  return c.u;
}

// y-in-LDS swizzle: uint4 slot q of node -> q ^ ((node>>1)&3).
__device__ __forceinline__ int yslot(int node, int q) {
  return (node << 2) | (q ^ ((node >> 1) & 3));
}

// ---------------- Kernel A: T = emb @ [W1_0 | W1_1] via MFMA -> fp16 [VOCAB][64] ----------------
__global__ __launch_bounds__(256) void k_setup(const float* __restrict__ emb,
    const float* __restrict__ W1, u32* __restrict__ Tg)
{
  const int tid = threadIdx.x;
  const int base = blockIdx.x * 128;
  const int lane = tid & 63, wv = tid >> 6;
  const int col = lane & 15, kg = lane >> 4;
  __shared__ __align__(16) unsigned short sX[128 * 64];   // 16 KB bf16 tile
  for (int s = tid; s < 1024; s += 256) {
    const int row = s >> 3, ck = s & 7;
    uint4 w = {0, 0, 0, 0};
    if (base + row < VOCAB) {
      const float2* __restrict__ p = (const float2*)(emb + (size_t)(base + row) * ED2 + ck * 8);
      float2 v0 = p[0], v1 = p[1], v2 = p[2];
      float2 v3; v3.x = 0.f; v3.y = 0.f;
      if (ck != 7) v3 = p[3];
      w.x = pack2(v0.x, v0.y); w.y = pack2(v1.x, v1.y);
      w.z = pack2(v2.x, v2.y); w.w = pack2(v3.x, v3.y);
    }
    ((uint4*)sX)[(row * 8 + ck) ^ (row & 7)] = w;
  }
  union { u32 u[4]; short8 v; } A[2][4];
#pragma unroll
  for (int kc = 0; kc < 2; ++kc)
#pragma unroll
    for (int hh = 0; hh < 4; ++hh) {
      const int tbl = hh >> 1;
      const int ch = ((hh & 1) * 16) + col;
#pragma unroll
      for (int jj = 0; jj < 4; ++jj) {
        const int k0 = kc * 32 + kg * 8 + 2 * jj;
        const int k1 = k0 + 1;
        const float wa = (k0 < 62) ? W1[(tbl * 62 + k0) * CH + ch] : 0.f;
        const float wb = (k1 < 62) ? W1[(tbl * 62 + k1) * CH + ch] : 0.f;
        A[kc][hh].u[jj] = pack2(wa, wb);
      }
    }
  __syncthreads();
  for (int t = wv; t < 8; t += 4) {
    const int ln = t * 16 + col;
    float4v acc[4];
#pragma unroll
    for (int hh = 0; hh < 4; ++hh) { acc[hh][0] = 0.f; acc[hh][1] = 0.f; acc[hh][2] = 0.f; acc[hh][3] = 0.f; }
#pragma unroll
    for (int kc = 0; kc < 2; ++kc) {
      const int idx8 = (ln * 8 + kc * 4 + kg) ^ (ln & 7);
      short8 bf = *(const short8*)(sX + idx8 * 8);
#pragma unroll
      for (int hh = 0; hh < 4; ++hh)
        acc[hh] = __builtin_amdgcn_mfma_f32_16x16x32_bf16(A[kc][hh].v, bf, acc[hh], 0, 0, 0);
    }
    const int row = base + ln;
    if (row < VOCAB) {
      u32* op = Tg + (size_t)row * 32;
#pragma unroll
      for (int hh = 0; hh < 4; ++hh) {
        uint2 s0 = { packh(acc[hh][0], acc[hh][1]), packh(acc[hh][2], acc[hh][3]) };
        *(uint2*)(op + hh * 8 + 2 * kg) = s0;
      }
    }
  }
}

// ---------------- Fused kernel: prep + GCN1 gather + layers 2,3,4 + tail ----------------
#define EDGEA(EP, K) { const int a16 = ((int)(EP)[(K) * 16]) ^ kg; \
  uint4 n = sy4[a16]; \
  a0h += u2h(n.x); a1h += u2h(n.y); a2h += u2h(n.z); a3h += u2h(n.w); }
#define EDGEB(EP, K) { const int a16 = ((int)(EP)[(K) * 16]) ^ kg; \
  uint4 n = sy4[a16]; \
  b0h += u2h(n.x); b1h += u2h(n.y); b2h += u2h(n.z); b3h += u2h(n.w); }
#define FLUSH { a0h += b0h; a1h += b1h; a2h += b2h; a3h += b3h; \
  zx[0] += (float)a0h.x; zx[1] += (float)a0h.y; \
  zx[2] += (float)a1h.x; zx[3] += (float)a1h.y; \
  zx[4] += (float)a2h.x; zx[5] += (float)a2h.y; \
  zx[6] += (float)a3h.x; zx[7] += (float)a3h.y; \
  a0h = hz; a1h = hz; a2h = hz; a3h = hz; \
  b0h = hz; b1h = hz; b2h = hz; b3h = hz; }
// rows padded to x2: legs are while16 -> if8 -> if4 -> if2, each exact (no over-read)
#define AGG_LOOP(EP) { int kk = 0; \
  while (kk + 16 <= md4) { \
    _Pragma("unroll") for (int e = 0; e < 16; e += 2) { EDGEA(EP, kk + e) EDGEB(EP, kk + e + 1) } \
    FLUSH \
    kk += 16; } \
  if (kk + 8 <= md4) { \
    _Pragma("unroll") for (int e = 0; e < 8; e += 2) { EDGEA(EP, kk + e) EDGEB(EP, kk + e + 1) } \
    kk += 8; } \
  if (kk + 4 <= md4) { \
    EDGEA(EP, kk) EDGEB(EP, kk + 1) EDGEA(EP, kk + 2) EDGEB(EP, kk + 3) \
    kk += 4; } \
  if (kk < md4) { EDGEA(EP, kk) EDGEB(EP, kk + 1) } \
  FLUSH }

template<int ACT>
__device__ __forceinline__ void gcn_pass32(
    u32* __restrict__ sy, const u16* __restrict__ s_ell,
    const u16* __restrict__ s_elloff, const float* __restrict__ s_dv,
    const u16* __restrict__ pvs,
    const int wv, const int col, const int kg,
    const short8 a0v, const short8 a1v, const float* __restrict__ bias8)
{
  const uint4* sy4 = (const uint4*)sy;
  const f16x2 hz = {(_Float16)0, (_Float16)0};
  u32 outs[3][4];
  int nodes[3];
#pragma unroll
  for (int p = 0; p < 3; ++p) {
    const int t = p * 16 + wv;
    const int pv = (t < NT16) ? (int)pvs[p] : 0xFFFF;
    const int node = (pv == 0xFFFF) ? NN : pv;
    nodes[p] = (pv == 0xFFFF) ? -1 : pv;
    int base = 0, md4 = 0;
    if (t < NT16) { base = s_elloff[t]; md4 = s_elloff[t + 1] - base; }
    base = __builtin_amdgcn_readfirstlane(base);
    md4 = __builtin_amdgcn_readfirstlane(md4);
    f16x2 a0h, a1h, a2h, a3h;
    f16x2 b0h = hz, b1h = hz, b2h = hz, b3h = hz;
    {
      uint4 u = sy4[yslot(node, kg)];          // self (dummy row = zeros)
      a0h = u2h(u.x); a1h = u2h(u.y); a2h = u2h(u.z); a3h = u2h(u.w);
    }
    float zx[8];
#pragma unroll
    for (int j = 0; j < 8; ++j) zx[j] = 0.f;
    const u16* ep = s_ell + base * 16 + col;
    AGG_LOOP(ep)
    const float dv = s_dv[node];               // dummy dv = 0
    float h[8];
#pragma unroll
    for (int j = 0; j < 8; ++j) {
      float t2 = fmaf(dv, zx[j], bias8[j]);
      float l = (t2 > 0.f) ? t2 : 0.01f * t2;
      h[j] = (ACT == 0) ? l : (l + t2);
    }
    union { u32 u[4]; short8 v; } ub;
#pragma unroll
    for (int jj = 0; jj < 4; ++jj) ub.u[jj] = pack2(h[2 * jj], h[2 * jj + 1]);
    float4v z4 = {0.f, 0.f, 0.f, 0.f};
    float4v d0 = __builtin_amdgcn_mfma_f32_16x16x32_bf16(a0v, ub.v, z4, 0, 0, 0);
    float4v d1 = __builtin_amdgcn_mfma_f32_16x16x32_bf16(a1v, ub.v, z4, 0, 0, 0);
    outs[p][0] = packh(d0[0] * dv, d0[1] * dv);
    outs[p][1] = packh(d0[2] * dv, d0[3] * dv);
    outs[p][2] = packh(d1[0] * dv, d1[1] * dv);
    outs[p][3] = packh(d1[2] * dv, d1[3] * dv);
  }
  __syncthreads();
#pragma unroll
  for (int p = 0; p < 3; ++p) {
    const int node = nodes[p];
    if (node >= 0) {
      const int sw = (node >> 1) & 3;
      u32* op = sy + node * 16;
      uint2 s0 = { outs[p][0], outs[p][1] };
      uint2 s1 = { outs[p][2], outs[p][3] };
      *(uint2*)(op + (((kg >> 1) ^ sw) << 2) + ((2 * kg) & 3)) = s0;
      *(uint2*)(op + (((2 + (kg >> 1)) ^ sw) << 2) + ((2 * kg) & 3)) = s1;
    }
  }
  __syncthreads();
}

__global__ __launch_bounds__(1024) void k_fused(
    const int* __restrict__ ids, const float* __restrict__ cont,
    const int* __restrict__ edges,
    const u32* __restrict__ T, const float* __restrict__ W1,
    const float* __restrict__ b1, const float* __restrict__ W2,
    const float* __restrict__ b2, const float* __restrict__ W3,
    const float* __restrict__ b3, const float* __restrict__ W4,
    const float* __restrict__ b4, const float* __restrict__ Wf1,
    const float* __restrict__ bf1, const float* __restrict__ Wf2,
    const float* __restrict__ bf2, float* __restrict__ out)
{
  const int b = blockIdx.x;
  const int tid = threadIdx.x;
  const int lane = tid & 63;
  const int wv = tid >> 6;          // wave 0..15
  const int col = lane & 15;
  const int kg = lane >> 4;

  extern __shared__ __align__(16) char smem[];
  // persistent regions
  u32*   s_y      = (u32*)smem;                     // 45760 B (715 rows; overlay home)
  u16*   s_ell    = (u16*)(smem + 45760);           // 13824
  u16*   s_elloff = (u16*)(smem + 59584);           // 96
  float* s_dv     = (float*)(smem + 59680);         // 2864 (incl dummy)
  float* s_h      = (float*)(smem + 62544);         // 2864 (Wc during staging; layer-4 out later)
  u16*   s_perm   = (u16*)(smem + 65408);           // 1440
  float* s_red    = (float*)smem;                   // aliases dead s_y (FC)
  float* s_u      = (float*)(smem + 8192);          // aliases dead s_y (FC)
  // phase-0 overlay inside s_y region
  int*   s_cnt    = (int*)smem;                     // 2856
  int*   s_csr    = (int*)(smem + 2944);            // 2856 (inclusive degree scan)
  u16*   s_rows16 = (u16*)(smem + 5888);            // 8192
  u16*   s_degP   = (u16*)(smem + 14080);           // 1440
  int*   s_md     = (int*)(smem + 15520);           // 256 (64 ints; hist then tile offsets)
  int*   s_wsum   = (int*)(smem + 15776);           // 64

  // ---------------- phase 0: per-batch prep entirely in LDS ----------------
  const int* __restrict__ er = edges + (size_t)b * 2 * EE;   // source (row)
  const int* __restrict__ ec = er + EE;                      // target (col)
  for (int i = tid; i < NN; i += 1024) s_cnt[i] = 0;
  if (tid < 96) s_h[tid] = W1[124 * 32 + tid];               // Wc cache
  __syncthreads();
  {
    const int4 ec4 = ((const int4*)ec)[tid];                 // 1024 x 4 = 4096 exactly
    atomicAdd(&s_cnt[ec4.x], 1);
    atomicAdd(&s_cnt[ec4.y], 1);
    atomicAdd(&s_cnt[ec4.z], 1);
    atomicAdd(&s_cnt[ec4.w], 1);
  }
  __syncthreads();
  const int deg = (tid < NN) ? s_cnt[tid] : 0;
  if (tid < NN) s_dv[tid] = rsqrtf((float)(deg + 1));
  if (tid == 0) s_dv[NN] = 0.f;
  // inclusive scan of degrees over 1024 slots (1 elem/thread)
  {
    int incl = deg;
#pragma unroll
    for (int d = 1; d < 64; d <<= 1) {
      int o = __shfl_up(incl, d, 64);
      if (lane >= d) incl += o;
    }
    if (lane == 63) s_wsum[wv] = incl;
    __syncthreads();
    if (wv == 0 && lane < 16) {
      int v = s_wsum[lane];
      int ic = v;
#pragma unroll
      for (int d = 1; d < 16; d <<= 1) {
        int o = __shfl_up(ic, d, 16);
        if (lane >= d) ic += o;
      }
      s_wsum[lane] = ic - v;   // exclusive wave offset
    }
    __syncthreads();
    incl += s_wsum[wv];
    if (tid < NN) s_csr[tid] = incl;
  }
  __syncthreads();
  for (int i = tid; i < NN; i += 1024) s_cnt[i] = 0;  // fill cursors
  __syncthreads();
  {
    const int4 ec4 = ((const int4*)ec)[tid];
    const int4 er4 = ((const int4*)er)[tid];
    {
      const int c = ec4.x; const int p = atomicAdd(&s_cnt[c], 1);
      s_rows16[(c ? s_csr[c - 1] : 0) + p] = (u16)er4.x;
    }
    {
      const int c = ec4.y; const int p = atomicAdd(&s_cnt[c], 1);
      s_rows16[(c ? s_csr[c - 1] : 0) + p] = (u16)er4.y;
    }
    {
      const int c = ec4.z; const int p = atomicAdd(&s_cnt[c], 1);
      s_rows16[(c ? s_csr[c - 1] : 0) + p] = (u16)er4.z;
    }
    {
      const int c = ec4.w; const int p = atomicAdd(&s_cnt[c], 1);
      s_rows16[(c ? s_csr[c - 1] : 0) + p] = (u16)er4.w;
    }
  }
  // degree-sorted perm (counting sort, 64 bins)
  if (tid < 64) s_md[tid] = 0;
  for (int i = tid; i < NPAD; i += 1024) { s_perm[i] = 0xFFFFu; s_degP[i] = 0; }
  __syncthreads();
  if (tid < NN) atomicAdd(&s_md[deg < 63 ? deg : 63], 1);
  __syncthreads();
  if (tid < 64) {
    int v = s_md[tid];
    int incl = v;
#pragma unroll
    for (int d = 1; d < 64; d <<= 1) {
      int o = __shfl_up(incl, d, 64);
      if (tid >= d) incl += o;
    }
    s_md[tid] = incl - v;
  }
  __syncthreads();
  if (tid < NN) {
    const int pos = atomicAdd(&s_md[deg < 63 ? deg : 63], 1);
    s_perm[pos] = (u16)tid;
    s_degP[pos] = (u16)deg;
  }
  __syncthreads();
  // per-tile max degree (pad2) + clamped exclusive scan
  if (tid < NT16) {
    int md = 0;
#pragma unroll
    for (int c = 0; c < 16; ++c) { int d = s_degP[tid * 16 + c]; md = d > md ? d : md; }
    s_md[tid] = (md + 1) & ~1;
  }
  __syncthreads();
  if (tid < 64) {
    int m = (tid < NT16) ? s_md[tid] : 0;
    int incl = m;
#pragma unroll
    for (int d = 1; d < 64; d <<= 1) {
      int o = __shfl_up(incl, d, 64);
      if (tid >= d) incl += o;
    }
    int excl = incl - m;
    if (excl > ELLR) excl = ELLR;
    if (tid < NT16) s_md[tid] = excl;
    if (tid == NT16 - 1) s_md[NT16] = (incl > ELLR) ? ELLR : incl;
  }
  __syncthreads();
  if (tid <= NT16) s_elloff[tid] = (u16)s_md[tid];
  // ELL fill straight into LDS (16 waves; pre-swizzled entries; pad -> dummy NN)
  for (int t = wv; t < NT16; t += 16) {
    const int base = s_md[t], md4 = s_md[t + 1] - base;
    for (int s = lane; s < md4 * 16; s += 64) {
      const int kk = s >> 4, c = s & 15;
      const int pv = s_perm[t * 16 + c];
      int r = NN;
      if (pv != 0xFFFF) {
        const int dg = s_degP[t * 16 + c];
        if (kk < dg) {
          const int off = pv ? s_csr[pv - 1] : 0;
          r = (int)s_rows16[off + kk];
        }
      }
      s_ell[base * 16 + s] = (u16)((r << 2) | ((r >> 1) & 3));
    }
  }
  __syncthreads();   // prep done; overlay region (s_cnt..s_wsum) is now dead

  // ---------------- phase B: GCN1 via table gather, (node, half) items ----------------
  {
    uint4* sy4w = (uint4*)s_y;
    if (tid < 4) { const uint4 z4 = {0, 0, 0, 0}; sy4w[yslot(NN, tid)] = z4; }
#pragma unroll 1
    for (int item = tid; item < 2 * NN; item += 1024) {
      const int node = item >> 1, half = item & 1;
      const int2 id2 = ((const int2*)ids)[(size_t)b * NN + node];
      const uint4* __restrict__ t0 = (const uint4*)(T + (size_t)id2.x * 32);        // ch 0..31
      const uint4* __restrict__ t1 = (const uint4*)(T + (size_t)id2.y * 32 + 16);   // ch 32..63
      uint4 qa = t0[2 * half], qb = t0[2 * half + 1];
      uint4 ra = t1[2 * half], rb = t1[2 * half + 1];
      const float* __restrict__ c3 = cont + ((size_t)b * NN + node) * 3;
      const float c0 = c3[0], c1 = c3[1], c2 = c3[2];
      const float dv = s_dv[node];
      const u32 qs[8] = { qa.x, qa.y, qa.z, qa.w, qb.x, qb.y, qb.z, qb.w };
      const u32 rs[8] = { ra.x, ra.y, ra.z, ra.w, rb.x, rb.y, rb.z, rb.w };
      u32 os[8];
#pragma unroll
      for (int s = 0; s < 8; ++s) {
        f16x2 a = u2h(qs[s]);
        f16x2 bb = u2h(rs[s]);
        const int ch = 16 * half + 2 * s;
        float v0 = (float)a.x + (float)bb.x;
        float v1 = (float)a.y + (float)bb.y;
        v0 = fmaf(c0, s_h[ch],      v0);
        v1 = fmaf(c0, s_h[ch + 1],  v1);
        v0 = fmaf(c1, s_h[32 + ch],     v0);
        v1 = fmaf(c1, s_h[32 + ch + 1], v1);
        v0 = fmaf(c2, s_h[64 + ch],     v0);
        v1 = fmaf(c2, s_h[64 + ch + 1], v1);
        os[s] = packh(v0 * dv, v1 * dv);
      }
      uint4 w0 = { os[0], os[1], os[2], os[3] };
      uint4 w1 = { os[4], os[5], os[6], os[7] };
      sy4w[yslot(node, 2 * half)] = w0;
      sy4w[yslot(node, 2 * half + 1)] = w1;
    }
  }
  u16 pvs[3];
#pragma unroll
  for (int p = 0; p < 3; ++p) {
    const int t = p * 16 + wv;
    pvs[p] = (t < NT16) ? s_perm[t * 16 + col] : (u16)0xFFFF;
  }
  const u16 pvt = (tid < NPAD) ? s_perm[tid] : (u16)0xFFFF;

  union { u32 u[4]; short8 v; } uaA0, uaA1, uaB0, uaB1;
#pragma unroll
  for (int jj = 0; jj < 4; ++jj) {
    uaA0.u[jj] = pack2(W2[(kg * 8 + 2 * jj) * CH + col],      W2[(kg * 8 + 2 * jj + 1) * CH + col]);
    uaA1.u[jj] = pack2(W2[(kg * 8 + 2 * jj) * CH + 16 + col], W2[(kg * 8 + 2 * jj + 1) * CH + 16 + col]);
    uaB0.u[jj] = pack2(W3[(kg * 8 + 2 * jj) * CH + col],      W3[(kg * 8 + 2 * jj + 1) * CH + col]);
    uaB1.u[jj] = pack2(W3[(kg * 8 + 2 * jj) * CH + 16 + col], W3[(kg * 8 + 2 * jj + 1) * CH + 16 + col]);
  }
  float b1r[8], b2r[8], b3r[8], w4r[8];
#pragma unroll
  for (int j = 0; j < 8; ++j) {
    b1r[j] = b1[kg * 8 + j];
    b2r[j] = b2[kg * 8 + j];
    b3r[j] = b3[kg * 8 + j];
    w4r[j] = W4[kg * 8 + j];
  }
  const float bb4 = b4[0];
  __syncthreads();

  gcn_pass32<0>(s_y, s_ell, s_elloff, s_dv, pvs, wv, col, kg, uaA0.v, uaA1.v, b1r);
  gcn_pass32<1>(s_y, s_ell, s_elloff, s_dv, pvs, wv, col, kg, uaB0.v, uaB1.v, b2r);

  // layer 4: agg + b3, lrelu+t, dot W4 (32->1), *dinv -> s_h
  {
    const uint4* sy4 = (const uint4*)s_y;
    const f16x2 hz = {(_Float16)0, (_Float16)0};
#pragma unroll
    for (int p = 0; p < 3; ++p) {
      const int t = p * 16 + wv;
      const int pv = (t < NT16) ? (int)pvs[p] : 0xFFFF;
      const int node = (pv == 0xFFFF) ? NN : pv;
      int base = 0, md4 = 0;
      if (t < NT16) { base = s_elloff[t]; md4 = s_elloff[t + 1] - base; }
      base = __builtin_amdgcn_readfirstlane(base);
      md4 = __builtin_amdgcn_readfirstlane(md4);
      f16x2 a0h, a1h, a2h, a3h;
      f16x2 b0h = hz, b1h = hz, b2h = hz, b3h = hz;
      {
        uint4 u = sy4[yslot(node, kg)];
        a0h = u2h(u.x); a1h = u2h(u.y); a2h = u2h(u.z); a3h = u2h(u.w);
      }
      float zx[8];
#pragma unroll
      for (int j = 0; j < 8; ++j) zx[j] = 0.f;
      const u16* ep = s_ell + base * 16 + col;
      AGG_LOOP(ep)
      const float dv = s_dv[node];
      float part = 0.f;
#pragma unroll
      for (int j = 0; j < 8; ++j) {
        float t2 = fmaf(dv, zx[j], b3r[j]);
        float l = (t2 > 0.f) ? t2 : 0.01f * t2;
        part = fmaf(l + t2, w4r[j], part);
      }
      part += __shfl_xor(part, 16, 64);
      part += __shfl_xor(part, 32, 64);
      if (pv != 0xFFFF && kg == 0) s_h[node] = part * dv;
    }
  }
  __syncthreads();
  if (tid == 1023) s_h[NN] = 0.f;
  __syncthreads();

  // tail aggregation via ELL: z = h[node] + sum h[e0>>2]; lrelu(dinv*z + b4)
  {
    float hval = 0.f;
    int node = -1;
    if (tid < NPAD && pvt != 0xFFFF) {
      node = (int)pvt;
      const int t = tid >> 4, c = tid & 15;
      const int base = s_elloff[t], md4 = s_elloff[t + 1] - base;
      float z = s_h[node];
      const u16* ep = s_ell + base * 16 + c;
      for (int kk = 0; kk < md4; ++kk) z += s_h[((int)ep[kk * 16]) >> 2];
      float t2 = fmaf(s_dv[node], z, bb4);
      hval = (t2 > 0.f) ? t2 : 0.01f * t2;
    }
    __syncthreads();
    if (node >= 0) s_h[node] = hval;
  }
  __syncthreads();

  // FC1: 714 -> 128, 8-way split-K
  const int j = tid & 127, q = tid >> 7;
  {
    const int n0 = (q * NN) >> 3, n1 = ((q + 1) * NN) >> 3;
    const float* __restrict__ w = Wf1 + j;
    float a0 = 0.f, a1 = 0.f;
    int n = n0;
#pragma unroll 4
    for (; n + 2 <= n1; n += 2) {
      a0 = fmaf(s_h[n], w[(size_t)n * 128], a0);
      a1 = fmaf(s_h[n + 1], w[(size_t)(n + 1) * 128], a1);
    }
    if (n < n1) a0 = fmaf(s_h[n], w[(size_t)n * 128], a0);
    s_red[tid] = a0 + a1;
  }
  __syncthreads();
  if (tid < 128) {
    float v = bf1[tid];
#pragma unroll
    for (int m = 0; m < 8; ++m) v += s_red[tid + 128 * m];
    s_u[tid] = fmaxf(v, 0.f);
  }
  __syncthreads();
  // FC2: 128 -> 128, 8-way split-K
  {
    const float* __restrict__ w = Wf2 + j;
    float a0 = 0.f, a1 = 0.f;
#pragma unroll
    for (int k = q * 16; k < q * 16 + 16; k += 2) {
      a0 = fmaf(s_u[k], w[(size_t)k * 128], a0);
      a1 = fmaf(s_u[k + 1], w[(size_t)(k + 1) * 128], a1);
    }
    s_red[tid] = a0 + a1;
  }
  __syncthreads();
  if (tid < 128) {
    float v = bf2[tid];
#pragma unroll
    for (int m = 0; m < 8; ++m) v += s_red[tid + 128 * m];
    out[(size_t)b * 128 + tid] = fmaxf(v, 0.f);
  }
}

extern "C" void kernel_launch(void* const* d_in, const int* in_sizes, int n_in,
                              void* d_out, int out_size, void* d_ws, size_t ws_size,
                              hipStream_t stream)
{
  (void)in_sizes; (void)n_in; (void)out_size; (void)ws_size;
  const int*   ids  = (const int*)d_in[0];
  const float* cont = (const float*)d_in[1];
  const int*   edges= (const int*)d_in[2];
  const float* emb  = (const float*)d_in[3];
  const float* W1   = (const float*)d_in[4];
  const float* b1   = (const float*)d_in[5];
  const float* W2   = (const float*)d_in[6];
  const float* b2   = (const float*)d_in[7];
  const float* W3   = (const float*)d_in[8];
  const float* b3   = (const float*)d_in[9];
  const float* W4   = (const float*)d_in[10];
  const float* b4   = (const float*)d_in[11];
  const float* Wf1  = (const float*)d_in[12];
  const float* bf1  = (const float*)d_in[13];
  const float* Wf2  = (const float*)d_in[14];
  const float* bf2  = (const float*)d_in[15];
  float* out = (float*)d_out;

  char* ws = (char*)d_ws;
  size_t off = 0;
  auto alloc = [&](size_t bytes) -> void* {
    void* p = ws + off;
    off = (off + bytes + 255) & ~(size_t)255;
    return p;
  };
  u32* T = (u32*)alloc((size_t)VOCAB * 32 * 4);   // fp16 [VOCAB][64]

  hipLaunchKernelGGL(k_setup, dim3(NPRE), dim3(256), 0, stream, emb, W1, T);
  hipLaunchKernelGGL(k_fused, dim3(BB), dim3(1024), DYN_LDS, stream,
                     ids, cont, edges, T, W1,
                     b1, W2, b2, W3, b3, W4, b4, Wf1, bf1, Wf2, bf2, out);
}